// Round 7
// baseline (6277.817 us; speedup 1.0000x reference)
//
#include <hip/hip_runtime.h>
#include <hip/hip_bf16.h>
#include <math.h>

#define DIM 128

typedef float v2f __attribute__((ext_vector_type(2)));

// DPP move: lane i <- lane i+N (row_shl:N, within row of 16), VALU-speed.
template<int CTRL>
__device__ inline float dpp_movf(float v) {
  int x = __builtin_amdgcn_update_dpp(0, __float_as_int(v), CTRL, 0xF, 0xF, true);
  return __int_as_float(x);
}

// ---------------- gather rows from embedding table ----------------
__global__ void gather_rows(const float* __restrict__ table, const int* __restrict__ idx,
                            float* __restrict__ dst, int n) {
  int i = blockIdx.x * blockDim.x + threadIdx.x;   // over n*32 float4s
  int total = n * 32;
  if (i >= total) return;
  int r = i >> 5, c = i & 31;
  const float4* src = (const float4*)table + (size_t)idx[r] * 32 + c;
  ((float4*)dst)[i] = *src;
}

// ---------------- generic NT GEMM ----------------
// C[n][m] = f(dot(A[n], B[permB(m)]) + bias[permB(m)]) * adj[n][m]
// PERMB: gate-interleave permutation m=4u+g -> row 128g+u (for LSTM Wx layout)
template<bool RELU, bool HASBIAS, bool HASADJ, bool PERMB>
__global__ __launch_bounds__(256) void gemm_nt(
    const float* __restrict__ A, const float* __restrict__ B,
    float* __restrict__ C, int ldc, int K,
    const float* __restrict__ bias,
    const float* __restrict__ adj, int ldadj)
{
  __shared__ float As[64][17];
  __shared__ float Bs[64][17];
  int tid = threadIdx.x;
  int tx = tid & 15, ty = tid >> 4;
  int rowBase = blockIdx.y * 64, colBase = blockIdx.x * 64;
  int lr = tid >> 2, lk = (tid & 3) * 4;
  int brow = colBase + lr;
  if (PERMB) brow = 128 * (brow & 3) + (brow >> 2);
  float acc[4][4] = {};
  for (int k0 = 0; k0 < K; k0 += 16) {
    float4 av = *(const float4*)&A[(size_t)(rowBase + lr) * K + k0 + lk];
    float4 bv = *(const float4*)&B[(size_t)brow * K + k0 + lk];
    As[lr][lk+0]=av.x; As[lr][lk+1]=av.y; As[lr][lk+2]=av.z; As[lr][lk+3]=av.w;
    Bs[lr][lk+0]=bv.x; Bs[lr][lk+1]=bv.y; Bs[lr][lk+2]=bv.z; Bs[lr][lk+3]=bv.w;
    __syncthreads();
#pragma unroll
    for (int kk = 0; kk < 16; ++kk) {
      float a0=As[ty*4+0][kk], a1=As[ty*4+1][kk], a2=As[ty*4+2][kk], a3=As[ty*4+3][kk];
      float b0=Bs[tx*4+0][kk], b1=Bs[tx*4+1][kk], b2=Bs[tx*4+2][kk], b3=Bs[tx*4+3][kk];
      acc[0][0]+=a0*b0; acc[0][1]+=a0*b1; acc[0][2]+=a0*b2; acc[0][3]+=a0*b3;
      acc[1][0]+=a1*b0; acc[1][1]+=a1*b1; acc[1][2]+=a1*b2; acc[1][3]+=a1*b3;
      acc[2][0]+=a2*b0; acc[2][1]+=a2*b1; acc[2][2]+=a2*b2; acc[2][3]+=a2*b3;
      acc[3][0]+=a3*b0; acc[3][1]+=a3*b1; acc[3][2]+=a3*b2; acc[3][3]+=a3*b3;
    }
    __syncthreads();
  }
  int row = rowBase + ty*4, col = colBase + tx*4;
#pragma unroll
  for (int i = 0; i < 4; ++i) {
    float aj[4] = {1.f,1.f,1.f,1.f};
    if (HASADJ) {
      float4 adjv = *(const float4*)&adj[(size_t)(row+i)*ldadj + col];
      aj[0]=adjv.x; aj[1]=adjv.y; aj[2]=adjv.z; aj[3]=adjv.w;
    }
    float v[4];
#pragma unroll
    for (int j = 0; j < 4; ++j) {
      float x = acc[i][j];
      if (HASBIAS) {
        int bidx = col + j;
        if (PERMB) bidx = 128 * (bidx & 3) + (bidx >> 2);
        x += bias[bidx];
      }
      if (HASADJ) x *= aj[j];
      if (RELU) x = fmaxf(x, 0.f);
      v[j] = x;
    }
    float* cp = &C[(size_t)(row+i)*ldc + col];   // 8B-aligned even at d_out+2
    *(float2*)cp = make_float2(v[0], v[1]);
    *(float2*)(cp+2) = make_float2(v[2], v[3]);
  }
}

// ---------------- row reduction: abs-sum (with eps floor) or mean ----------------
template<bool ABS>
__global__ void row_reduce(const float* __restrict__ W, int ld, int M,
                           float* __restrict__ out, float p /*eps or 1/M*/) {
  int n = blockIdx.x;
  const float* row = W + (size_t)n * ld;
  float s = 0;
  for (int m = threadIdx.x; m < M; m += 256) {
    float v = row[m];
    s += ABS ? fabsf(v) : v;
  }
  __shared__ float red[256];
  red[threadIdx.x] = s; __syncthreads();
  for (int k = 128; k > 0; k >>= 1) {
    if (threadIdx.x < k) red[threadIdx.x] += red[threadIdx.x + k];
    __syncthreads();
  }
  if (threadIdx.x == 0) out[n] = ABS ? fmaxf(red[0], p) : red[0] * p;
}

// ---------------- column mean, 2-stage ----------------
__global__ void colmean_part(const float* __restrict__ W, int ld, int rows_per,
                             float* __restrict__ part, int M) {
  int m = blockIdx.x * blockDim.x + threadIdx.x;
  int n0 = blockIdx.y * rows_per;
  float s = 0;
  for (int n = 0; n < rows_per; ++n) s += W[(size_t)(n0 + n) * ld + m];
  part[(size_t)blockIdx.y * M + m] = s;
}
__global__ void colmean_fin(const float* __restrict__ part, int M, int nparts,
                            float* __restrict__ out, float inv) {
  int m = blockIdx.x * blockDim.x + threadIdx.x;
  float s = 0;
  for (int k = 0; k < nparts; ++k) s += part[(size_t)k * M + m];
  out[m] = s * inv;
}

// ---------------- attn @ hs with K-split ----------------
__global__ __launch_bounds__(256) void attn_av(
    const float* __restrict__ attn, int ld,
    const float* __restrict__ hs, float* __restrict__ pt,
    int chunk, int N)
{
  int r0 = blockIdx.x * 32;
  int kc = blockIdx.y;
  int m0 = kc * chunk;
  __shared__ float Hs[32][DIM];
  __shared__ float As[32][33];
  int tid = threadIdx.x;
  int tx = tid & 31, ry = tid >> 5;
  float acc[4][4] = {};
  for (int mt = 0; mt < chunk; mt += 32) {
#pragma unroll
    for (int q = 0; q < 4; ++q) {
      int f = q * 256 + tid; int hr = f >> 5, hc = (f & 31) * 4;
      *(float4*)&Hs[hr][hc] = *(const float4*)&hs[(size_t)(m0 + mt + hr) * DIM + hc];
    }
    {
      int ar = tid >> 3, ac = (tid & 7) * 4;
      const float* src = &attn[(size_t)(r0 + ar) * ld + m0 + mt + ac];
      float2 u = *(const float2*)src; float2 w = *(const float2*)(src + 2);
      As[ar][ac] = u.x; As[ar][ac+1] = u.y; As[ar][ac+2] = w.x; As[ar][ac+3] = w.y;
    }
    __syncthreads();
#pragma unroll
    for (int mm = 0; mm < 32; ++mm) {
      float4 h4 = *(const float4*)&Hs[mm][tx * 4];
      float a0 = As[ry*4+0][mm], a1 = As[ry*4+1][mm], a2 = As[ry*4+2][mm], a3 = As[ry*4+3][mm];
      acc[0][0]+=a0*h4.x; acc[0][1]+=a0*h4.y; acc[0][2]+=a0*h4.z; acc[0][3]+=a0*h4.w;
      acc[1][0]+=a1*h4.x; acc[1][1]+=a1*h4.y; acc[1][2]+=a1*h4.z; acc[1][3]+=a1*h4.w;
      acc[2][0]+=a2*h4.x; acc[2][1]+=a2*h4.y; acc[2][2]+=a2*h4.z; acc[2][3]+=a2*h4.w;
      acc[3][0]+=a3*h4.x; acc[3][1]+=a3*h4.y; acc[3][2]+=a3*h4.z; acc[3][3]+=a3*h4.w;
    }
    __syncthreads();
  }
#pragma unroll
  for (int i = 0; i < 4; ++i) {
    float4 v = make_float4(acc[i][0], acc[i][1], acc[i][2], acc[i][3]);
    *(float4*)&pt[((size_t)kc * N + r0 + ry*4 + i) * DIM + tx*4] = v;
  }
}

// xs[n][d] += (sum_kc pt[kc][n][d]) / denom[n]
__global__ void axpy_reduce(const float* __restrict__ pt, const float* __restrict__ denom,
                            float* __restrict__ xs, int total) {
  int i = blockIdx.x * blockDim.x + threadIdx.x;
  if (i >= total) return;
  float s = 0;
#pragma unroll
  for (int k = 0; k < 8; ++k) s += pt[(size_t)k * total + i];
  xs[i] += s / denom[i >> 7];
}

__global__ void add_vec(const float* __restrict__ a, const float* __restrict__ b,
                        float* __restrict__ o, int n) {
  int i = blockIdx.x * blockDim.x + threadIdx.x;
  if (i < n) o[i] = a[i] + b[i];
}

// ---------------- bidirectional LSTM v6 ----------------
// 1024 thr = 16 waves = 4/SIMD (the HW max for this block size -> VGPR cap 128,
// and max-occupancy == keeping weights resident, so the allocator keeps them).
// Thread = (unit u, gate g, k-half q): lane = 8*(u%8) + 2*g + q, wave = u/8.
// Per thread: 64 weights (k in [64q,64q+64)) as 32 named+pinned v2f = 64 VGPR.
// Per step: 32 pk_fma; q-sum via row_shl:1; wx added AFTER q-sum; activation;
// gate gather via row_shl:2/4/6 (within row-of-16). Zero weight traffic/step.
#define REP16(X) X(0) X(1) X(2) X(3) X(4) X(5) X(6) X(7) X(8) X(9) X(10) X(11) \
  X(12) X(13) X(14) X(15)

__global__ __launch_bounds__(1024, 4) void lstm_kernel(
    const float* __restrict__ Whh,   // [2][512][128] (original layout)
    const float* __restrict__ Wxp,   // [2][M][512]  gate-interleaved: col 4u+g
    float* __restrict__ xs_rnn,      // [M][256]  (stores relu(h))
    int M)
{
  int dir = blockIdx.x;
  int tid = threadIdx.x;
  int w = tid >> 6, lane = tid & 63;
  int i = lane >> 3;                 // u = w*8 + i
  int g = (lane >> 1) & 3;           // gate 0:i 1:f 2:g 3:o
  int q = lane & 1;                  // k-half
  int u = w * 8 + i;
  const float4* wrow4 = (const float4*)(Whh + ((size_t)dir * 512 + g * 128 + u) * DIM + q * 64);

#define DECLW(r) v2f wa##r, wb##r;
  REP16(DECLW)
#define LOADW(r) { float4 v = wrow4[r]; wa##r = v2f{v.x, v.y}; wb##r = v2f{v.z, v.w}; }
  REP16(LOADW)
  // pin: asm-defined values cannot be rematerialized from memory
#define PINW(r) asm volatile("" : "+v"(wa##r), "+v"(wb##r));
  REP16(PINW)

  __shared__ __align__(16) float hbuf[2][DIM];
  if (tid < DIM) hbuf[0][tid] = 0.f;
  float c = 0.f;
  __syncthreads();

  const float* WxD = Wxp + (size_t)dir * M * 512;
  int wxcol = (w << 5) + (lane >> 1);          // = 4u+g
  int t0 = dir ? (M - 1) : 0;
  float wx = WxD[(size_t)t0 * 512 + wxcol];
  for (int s = 0; s < M; ++s) {
    int t = dir ? (M - 1 - s) : s;
    float wxn = 0.f;
    if (s + 1 < M) {
      int tn = dir ? (M - 2 - s) : (s + 1);
      wxn = WxD[(size_t)tn * 512 + wxcol];     // prefetch next step
    }
    int cur = s & 1;
    const float4* hb4 = (const float4*)(hbuf[cur]) + q * 16;  // k-half [64q,64q+64)
    v2f accA = {0.f, 0.f}, accB = {0.f, 0.f};
#define DOTW(r) { float4 hv = hb4[r]; \
    accA = __builtin_elementwise_fma(wa##r, v2f{hv.x, hv.y}, accA); \
    accB = __builtin_elementwise_fma(wb##r, v2f{hv.z, hv.w}, accB); }
    REP16(DOTW)
    float zp = (accA.x + accA.y) + (accB.x + accB.y);
    float z = zp + dpp_movf<0x101>(zp);        // q-sum (valid at even lanes)
    z += wx;                                   // bias AFTER q-sum (once)
    // activation: sigmoid for i,f,o; tanh for g (tanh(z) = 2*sigmoid(2z)-1)
    float zz = (g == 2) ? 2.f * z : z;
    float sg = 1.f / (1.f + __expf(-zz));
    float av = (g == 2) ? 2.f * sg - 1.f : sg;
    // gather f,g,o into the i-gate lane (lane 8i): gates 2 lanes apart
    float fv = dpp_movf<0x102>(av);
    float gv = dpp_movf<0x104>(av);
    float ov = dpp_movf<0x106>(av);
    if ((lane & 7) == 0) {
      c = fv * c + av * gv;
      float ec = __expf(-2.f * c);
      float th = (1.f - ec) / (1.f + ec);   // tanh(c)
      float hv = ov * th;
      hbuf[cur ^ 1][u] = hv;
      xs_rnn[(size_t)t * (2 * DIM) + dir * DIM + u] = fmaxf(hv, 0.f);
    }
    wx = wxn;
    __syncthreads();   // single barrier: h write visible before next-step read
  }
#undef DOTW
#undef PINW
#undef LOADW
#undef DECLW
}

// ---------------- weighted mean pooling ----------------
__global__ void pool_vec(const float* __restrict__ mat, const float* __restrict__ wv,
                         int n, float* __restrict__ out, float inv) {
  int t = threadIdx.x; int g = t >> 7, d = t & 127;
  float acc = 0;
  for (int r = g; r < n; r += 8) acc += wv[r] * mat[(size_t)r * DIM + d];
  __shared__ float red[1024];
  red[t] = acc; __syncthreads();
  if (g == 0) {
    float s = acc;
#pragma unroll
    for (int k = 1; k < 8; ++k) s += red[k * 128 + d];
    out[d] = s * inv;
  }
}

// ---------------- output MLP ----------------
__global__ void mlp_kernel(const float* __restrict__ cvec, const float* __restrict__ pvec,
                           const float* __restrict__ Wo, const float* __restrict__ bo,
                           const float* __restrict__ Wi, const float* __restrict__ bi,
                           float* __restrict__ out) {
  __shared__ float buf0[256], buf1[256];
  int t = threadIdx.x;
  buf0[t] = (t < 128) ? cvec[t] : pvec[t - 128];
  __syncthreads();
  {
    const float* W = Wo;                 // layer 0
    float s = bo[t];
    for (int v = 0; v < 256; ++v) s += W[t * 256 + v] * buf0[v];
    buf1[t] = fmaxf(s, 0.f);
  }
  __syncthreads();
  {
    const float* W = Wo + 256 * 256;     // layer 1
    float s = bo[256 + t];
    for (int v = 0; v < 256; ++v) s += W[t * 256 + v] * buf1[v];
    buf0[t] = fmaxf(s, 0.f);
  }
  __syncthreads();
  if (t < 2) {
    float s = bi[t];
    for (int v = 0; v < 256; ++v) s += Wi[t * 256 + v] * buf0[v];
    out[t] = s;
  }
}

extern "C" void kernel_launch(void* const* d_in, const int* in_sizes, int n_in,
                              void* d_out, int out_size, void* d_ws, size_t ws_size,
                              hipStream_t stream) {
  const int*   fingerprints = (const int*)d_in[0];
  const float* adjacency    = (const float*)d_in[1];
  const int*   words        = (const int*)d_in[2];
  const float* emb_fp       = (const float*)d_in[3];
  const float* emb_word     = (const float*)d_in[4];
  const float* Wg  = (const float*)d_in[5];
  const float* bg  = (const float*)d_in[6];
  const float* Wih = (const float*)d_in[7];
  const float* Whh = (const float*)d_in[8];
  const float* bih = (const float*)d_in[9];
  const float* bhh = (const float*)d_in[10];
  const float* Wc  = (const float*)d_in[11];
  const float* bc  = (const float*)d_in[12];
  const float* Wp  = (const float*)d_in[13];
  const float* bp  = (const float*)d_in[14];
  const float* Wo  = (const float*)d_in[15];
  const float* bo  = (const float*)d_in[16];
  const float* Wi  = (const float*)d_in[17];
  const float* bi  = (const float*)d_in[18];

  const int N = in_sizes[0];
  const int M = in_sizes[2];
  const int LGAT = in_sizes[5] / (DIM * DIM);

  float* out  = (float*)d_out;
  float* attn = out + 2;            // [N][M]: scratch during GAT, final `weights` at end

  float* ws = (float*)d_ws;
  size_t off = 0;
  auto alloc = [&](size_t nf) { float* p = ws + off; off += (nf + 3) & ~(size_t)3; return p; };
  float* xs     = alloc((size_t)N * DIM);
  float* hs     = alloc((size_t)N * DIM);
  float* wvb    = alloc((size_t)M * DIM);
  float* denom  = alloc(N);
  float* pt     = alloc((size_t)8 * N * DIM);    // K-split partials; aliased as Wx afterwards
  float* Wx     = pt;                            // [2][M][512] gate-interleaved
  float* xs_rnn = alloc((size_t)M * 2 * DIM);
  float* hp     = alloc((size_t)M * DIM);
  float* hmat   = alloc((size_t)N * DIM);
  float* bsum   = alloc(1024);
  float* wcomp  = alloc(N);
  float* wprot  = alloc(M);
  float* cvec   = alloc(DIM);
  float* pvec   = alloc(DIM);
  float* cpart  = alloc((size_t)32 * M);
  (void)ws_size; (void)n_in; (void)out_size;

  // ---- embeddings ----
  gather_rows<<<(N * 32 + 255) / 256, 256, 0, stream>>>(emb_fp, fingerprints, xs, N);
  gather_rows<<<(M * 32 + 255) / 256, 256, 0, stream>>>(emb_word, words, wvb, M);

  // ---- GAT layers ----
  for (int l = 0; l < LGAT; ++l) {
    gemm_nt<true, true, false, false><<<dim3(DIM / 64, N / 64), 256, 0, stream>>>(
        xs, Wg + (size_t)l * DIM * DIM, hs, DIM, DIM, bg + l * DIM, nullptr, 0);
    gemm_nt<false, false, true, false><<<dim3(M / 64, N / 64), 256, 0, stream>>>(
        hs, hs, attn, M, DIM, nullptr, adjacency, M);
    row_reduce<true><<<N, 256, 0, stream>>>(attn, M, M, denom, 1e-12f);
    attn_av<<<dim3(N / 32, 8), 256, 0, stream>>>(attn, M, hs, pt, M / 8, N);
    axpy_reduce<<<(N * DIM) / 256, 256, 0, stream>>>(pt, denom, xs, N * DIM);
  }

  // ---- LSTM precompute (gate-interleaved Wx) + run ----
  add_vec<<<4, 256, 0, stream>>>(bih, bhh, bsum, 1024);
  for (int d = 0; d < 2; ++d) {
    gemm_nt<false, true, false, true><<<dim3(512 / 64, M / 64), 256, 0, stream>>>(
        wvb, Wih + (size_t)d * 512 * DIM, Wx + (size_t)d * M * 512, 512, DIM,
        bsum + d * 512, nullptr, 0);
  }
  lstm_kernel<<<2, 1024, 0, stream>>>(Whh, Wx, xs_rnn, M);

  // ---- cross-attention pooling ----
  gemm_nt<true, true, false, false><<<dim3(DIM / 64, M / 64), 256, 0, stream>>>(
      xs_rnn, Wp, hp, DIM, 2 * DIM, bp, nullptr, 0);
  gemm_nt<true, true, false, false><<<dim3(DIM / 64, N / 64), 256, 0, stream>>>(
      xs, Wc, hmat, DIM, DIM, bc, nullptr, 0);
  gemm_nt<false, false, false, false><<<dim3(M / 64, N / 64), 256, 0, stream>>>(
      hmat, hp, attn, M, DIM, nullptr, nullptr, 0);   // final `weights` output
  row_reduce<false><<<N, 256, 0, stream>>>(attn, M, M, wcomp, 1.f / (float)M);
  colmean_part<<<dim3(M / 256, 32), 256, 0, stream>>>(attn, M, N / 32, cpart, M);
  colmean_fin<<<M / 256, 256, 0, stream>>>(cpart, M, 32, wprot, 1.f / (float)N);
  pool_vec<<<1, 1024, 0, stream>>>(hmat, wcomp, N, cvec, 1.f / (float)N);
  pool_vec<<<1, 1024, 0, stream>>>(hp, wprot, M, pvec, 1.f / (float)M);

  // ---- output MLP ----
  mlp_kernel<<<1, 256, 0, stream>>>(cvec, pvec, Wo, bo, Wi, bi, out);
}

// Round 8
// 4243.554 us; speedup vs baseline: 1.4794x; 1.4794x over previous
//
#include <hip/hip_runtime.h>
#include <hip/hip_bf16.h>
#include <math.h>

#define DIM 128

typedef float v2f __attribute__((ext_vector_type(2)));

// DPP move: lane i <- lane i+N (row_shl:N, within row of 16), VALU-speed.
template<int CTRL>
__device__ inline float dpp_movf(float v) {
  int x = __builtin_amdgcn_update_dpp(0, __float_as_int(v), CTRL, 0xF, 0xF, true);
  return __int_as_float(x);
}

// ---------------- gather rows from embedding table ----------------
__global__ void gather_rows(const float* __restrict__ table, const int* __restrict__ idx,
                            float* __restrict__ dst, int n) {
  int i = blockIdx.x * blockDim.x + threadIdx.x;   // over n*32 float4s
  int total = n * 32;
  if (i >= total) return;
  int r = i >> 5, c = i & 31;
  const float4* src = (const float4*)table + (size_t)idx[r] * 32 + c;
  ((float4*)dst)[i] = *src;
}

// ---------------- generic NT GEMM ----------------
// C[n][m] = f(dot(A[n], B[permB(m)]) + bias[permB(m)]) * adj[n][m]
// PERMB: gate-interleave permutation m=4u+g -> row 128g+u (for LSTM Wx layout)
template<bool RELU, bool HASBIAS, bool HASADJ, bool PERMB>
__global__ __launch_bounds__(256) void gemm_nt(
    const float* __restrict__ A, const float* __restrict__ B,
    float* __restrict__ C, int ldc, int K,
    const float* __restrict__ bias,
    const float* __restrict__ adj, int ldadj)
{
  __shared__ float As[64][17];
  __shared__ float Bs[64][17];
  int tid = threadIdx.x;
  int tx = tid & 15, ty = tid >> 4;
  int rowBase = blockIdx.y * 64, colBase = blockIdx.x * 64;
  int lr = tid >> 2, lk = (tid & 3) * 4;
  int brow = colBase + lr;
  if (PERMB) brow = 128 * (brow & 3) + (brow >> 2);
  float acc[4][4] = {};
  for (int k0 = 0; k0 < K; k0 += 16) {
    float4 av = *(const float4*)&A[(size_t)(rowBase + lr) * K + k0 + lk];
    float4 bv = *(const float4*)&B[(size_t)brow * K + k0 + lk];
    As[lr][lk+0]=av.x; As[lr][lk+1]=av.y; As[lr][lk+2]=av.z; As[lr][lk+3]=av.w;
    Bs[lr][lk+0]=bv.x; Bs[lr][lk+1]=bv.y; Bs[lr][lk+2]=bv.z; Bs[lr][lk+3]=bv.w;
    __syncthreads();
#pragma unroll
    for (int kk = 0; kk < 16; ++kk) {
      float a0=As[ty*4+0][kk], a1=As[ty*4+1][kk], a2=As[ty*4+2][kk], a3=As[ty*4+3][kk];
      float b0=Bs[tx*4+0][kk], b1=Bs[tx*4+1][kk], b2=Bs[tx*4+2][kk], b3=Bs[tx*4+3][kk];
      acc[0][0]+=a0*b0; acc[0][1]+=a0*b1; acc[0][2]+=a0*b2; acc[0][3]+=a0*b3;
      acc[1][0]+=a1*b0; acc[1][1]+=a1*b1; acc[1][2]+=a1*b2; acc[1][3]+=a1*b3;
      acc[2][0]+=a2*b0; acc[2][1]+=a2*b1; acc[2][2]+=a2*b2; acc[2][3]+=a2*b3;
      acc[3][0]+=a3*b0; acc[3][1]+=a3*b1; acc[3][2]+=a3*b2; acc[3][3]+=a3*b3;
    }
    __syncthreads();
  }
  int row = rowBase + ty*4, col = colBase + tx*4;
#pragma unroll
  for (int i = 0; i < 4; ++i) {
    float aj[4] = {1.f,1.f,1.f,1.f};
    if (HASADJ) {
      float4 adjv = *(const float4*)&adj[(size_t)(row+i)*ldadj + col];
      aj[0]=adjv.x; aj[1]=adjv.y; aj[2]=adjv.z; aj[3]=adjv.w;
    }
    float v[4];
#pragma unroll
    for (int j = 0; j < 4; ++j) {
      float x = acc[i][j];
      if (HASBIAS) {
        int bidx = col + j;
        if (PERMB) bidx = 128 * (bidx & 3) + (bidx >> 2);
        x += bias[bidx];
      }
      if (HASADJ) x *= aj[j];
      if (RELU) x = fmaxf(x, 0.f);
      v[j] = x;
    }
    float* cp = &C[(size_t)(row+i)*ldc + col];   // 8B-aligned even at d_out+2
    *(float2*)cp = make_float2(v[0], v[1]);
    *(float2*)(cp+2) = make_float2(v[2], v[3]);
  }
}

// ---------------- row reduction: abs-sum (with eps floor) or mean ----------------
template<bool ABS>
__global__ void row_reduce(const float* __restrict__ W, int ld, int M,
                           float* __restrict__ out, float p /*eps or 1/M*/) {
  int n = blockIdx.x;
  const float* row = W + (size_t)n * ld;
  float s = 0;
  for (int m = threadIdx.x; m < M; m += 256) {
    float v = row[m];
    s += ABS ? fabsf(v) : v;
  }
  __shared__ float red[256];
  red[threadIdx.x] = s; __syncthreads();
  for (int k = 128; k > 0; k >>= 1) {
    if (threadIdx.x < k) red[threadIdx.x] += red[threadIdx.x + k];
    __syncthreads();
  }
  if (threadIdx.x == 0) out[n] = ABS ? fmaxf(red[0], p) : red[0] * p;
}

// ---------------- column mean, 2-stage ----------------
__global__ void colmean_part(const float* __restrict__ W, int ld, int rows_per,
                             float* __restrict__ part, int M) {
  int m = blockIdx.x * blockDim.x + threadIdx.x;
  int n0 = blockIdx.y * rows_per;
  float s = 0;
  for (int n = 0; n < rows_per; ++n) s += W[(size_t)(n0 + n) * ld + m];
  part[(size_t)blockIdx.y * M + m] = s;
}
__global__ void colmean_fin(const float* __restrict__ part, int M, int nparts,
                            float* __restrict__ out, float inv) {
  int m = blockIdx.x * blockDim.x + threadIdx.x;
  float s = 0;
  for (int k = 0; k < nparts; ++k) s += part[(size_t)k * M + m];
  out[m] = s * inv;
}

// ---------------- attn @ hs with K-split ----------------
__global__ __launch_bounds__(256) void attn_av(
    const float* __restrict__ attn, int ld,
    const float* __restrict__ hs, float* __restrict__ pt,
    int chunk, int N)
{
  int r0 = blockIdx.x * 32;
  int kc = blockIdx.y;
  int m0 = kc * chunk;
  __shared__ float Hs[32][DIM];
  __shared__ float As[32][33];
  int tid = threadIdx.x;
  int tx = tid & 31, ry = tid >> 5;
  float acc[4][4] = {};
  for (int mt = 0; mt < chunk; mt += 32) {
#pragma unroll
    for (int q = 0; q < 4; ++q) {
      int f = q * 256 + tid; int hr = f >> 5, hc = (f & 31) * 4;
      *(float4*)&Hs[hr][hc] = *(const float4*)&hs[(size_t)(m0 + mt + hr) * DIM + hc];
    }
    {
      int ar = tid >> 3, ac = (tid & 7) * 4;
      const float* src = &attn[(size_t)(r0 + ar) * ld + m0 + mt + ac];
      float2 u = *(const float2*)src; float2 w = *(const float2*)(src + 2);
      As[ar][ac] = u.x; As[ar][ac+1] = u.y; As[ar][ac+2] = w.x; As[ar][ac+3] = w.y;
    }
    __syncthreads();
#pragma unroll
    for (int mm = 0; mm < 32; ++mm) {
      float4 h4 = *(const float4*)&Hs[mm][tx * 4];
      float a0 = As[ry*4+0][mm], a1 = As[ry*4+1][mm], a2 = As[ry*4+2][mm], a3 = As[ry*4+3][mm];
      acc[0][0]+=a0*h4.x; acc[0][1]+=a0*h4.y; acc[0][2]+=a0*h4.z; acc[0][3]+=a0*h4.w;
      acc[1][0]+=a1*h4.x; acc[1][1]+=a1*h4.y; acc[1][2]+=a1*h4.z; acc[1][3]+=a1*h4.w;
      acc[2][0]+=a2*h4.x; acc[2][1]+=a2*h4.y; acc[2][2]+=a2*h4.z; acc[2][3]+=a2*h4.w;
      acc[3][0]+=a3*h4.x; acc[3][1]+=a3*h4.y; acc[3][2]+=a3*h4.z; acc[3][3]+=a3*h4.w;
    }
    __syncthreads();
  }
#pragma unroll
  for (int i = 0; i < 4; ++i) {
    float4 v = make_float4(acc[i][0], acc[i][1], acc[i][2], acc[i][3]);
    *(float4*)&pt[((size_t)kc * N + r0 + ry*4 + i) * DIM + tx*4] = v;
  }
}

// xs[n][d] += (sum_kc pt[kc][n][d]) / denom[n]
__global__ void axpy_reduce(const float* __restrict__ pt, const float* __restrict__ denom,
                            float* __restrict__ xs, int total) {
  int i = blockIdx.x * blockDim.x + threadIdx.x;
  if (i >= total) return;
  float s = 0;
#pragma unroll
  for (int k = 0; k < 8; ++k) s += pt[(size_t)k * total + i];
  xs[i] += s / denom[i >> 7];
}

__global__ void add_vec(const float* __restrict__ a, const float* __restrict__ b,
                        float* __restrict__ o, int n) {
  int i = blockIdx.x * blockDim.x + threadIdx.x;
  if (i < n) o[i] = a[i] + b[i];
}

// ---------------- bidirectional LSTM v7 ----------------
// Round-5 structure (best passing: full-k dot/thread, broadcast h reads,
// row_shl gate gather) with ONE change: amdgpu_waves_per_eu(2,2).
// Theory: the scheduler's REMAT of the 32 weight dwordx4 loads per step
// (rounds 2-7: VGPR stuck at 44-80) is driven by a default occupancy TARGET;
// clamping max waves/EU to 2 removes the incentive, letting the 128 weight
// VGPRs stay live across the 4096-step loop.
#define REP32(X) X(0) X(1) X(2) X(3) X(4) X(5) X(6) X(7) X(8) X(9) X(10) X(11) \
  X(12) X(13) X(14) X(15) X(16) X(17) X(18) X(19) X(20) X(21) X(22) X(23) \
  X(24) X(25) X(26) X(27) X(28) X(29) X(30) X(31)

__global__ void
__attribute__((amdgpu_flat_work_group_size(512, 512), amdgpu_waves_per_eu(2, 2)))
lstm_kernel(
    const float* __restrict__ Whh,   // [2][512][128] (original layout)
    const float* __restrict__ Wxp,   // [2][M][512]  gate-interleaved: col 4u+g
    float* __restrict__ xs_rnn,      // [M][256]  (stores relu(h))
    int M)
{
  int dir = blockIdx.x;
  int tid = threadIdx.x;
  int w = tid >> 6, lane = tid & 63;
  int u = w * 16 + (lane >> 2);      // hidden unit 0..127
  int g = lane & 3;                  // gate 0:i 1:f 2:g 3:o
  const float4* wrow4 = (const float4*)(Whh + ((size_t)dir * 512 + g * 128 + u) * DIM);

#define DECLW(r) v2f wa##r, wb##r;
  REP32(DECLW)
#define LOADW(r) { float4 v = wrow4[r]; wa##r = v2f{v.x, v.y}; wb##r = v2f{v.z, v.w}; }
  REP32(LOADW)

  __shared__ __align__(16) float hbuf[2][DIM];
  if (tid < DIM) hbuf[0][tid] = 0.f;
  float c = 0.f;
  __syncthreads();

  const float* WxD = Wxp + (size_t)dir * M * 512;
  int t0 = dir ? (M - 1) : 0;
  float wx = WxD[(size_t)t0 * 512 + tid];
  for (int s = 0; s < M; ++s) {
    int t = dir ? (M - 1 - s) : s;
    float wxn = 0.f;
    if (s + 1 < M) {
      int tn = dir ? (M - 2 - s) : (s + 1);
      wxn = WxD[(size_t)tn * 512 + tid];   // prefetch next step (coalesced dword)
    }
    int cur = s & 1;
    const float4* hb4 = (const float4*)hbuf[cur];
    v2f accA = {0.f, 0.f}, accB = {0.f, 0.f};
#define DOTW(r) { float4 hv = hb4[r]; \
    accA = __builtin_elementwise_fma(wa##r, v2f{hv.x, hv.y}, accA); \
    accB = __builtin_elementwise_fma(wb##r, v2f{hv.z, hv.w}, accB); }
    REP32(DOTW)
    float z = (accA.x + accA.y) + (accB.x + accB.y) + wx;
    // activation: sigmoid for i,f,o; tanh for g (tanh(z) = 2*sigmoid(2z)-1)
    float zz = (g == 2) ? 2.f * z : z;
    float sg = 1.f / (1.f + __expf(-zz));
    float av = (g == 2) ? 2.f * sg - 1.f : sg;
    // gather f,g,o gates into g==0 lane: row_shl:1/2/3 => lane i <- lane i+n
    float fv = dpp_movf<0x101>(av);
    float gv = dpp_movf<0x102>(av);
    float ov = dpp_movf<0x103>(av);
    if (g == 0) {
      c = fv * c + av * gv;
      float ec = __expf(-2.f * c);
      float th = (1.f - ec) / (1.f + ec);   // tanh(c)
      float hv = ov * th;
      hbuf[cur ^ 1][u] = hv;
      xs_rnn[(size_t)t * (2 * DIM) + dir * DIM + u] = fmaxf(hv, 0.f);
    }
    wx = wxn;
    __syncthreads();   // single barrier: h write visible before next-step read
  }
#undef DOTW
#undef LOADW
#undef DECLW
}

// ---------------- weighted mean pooling ----------------
__global__ void pool_vec(const float* __restrict__ mat, const float* __restrict__ wv,
                         int n, float* __restrict__ out, float inv) {
  int t = threadIdx.x; int g = t >> 7, d = t & 127;
  float acc = 0;
  for (int r = g; r < n; r += 8) acc += wv[r] * mat[(size_t)r * DIM + d];
  __shared__ float red[1024];
  red[t] = acc; __syncthreads();
  if (g == 0) {
    float s = acc;
#pragma unroll
    for (int k = 1; k < 8; ++k) s += red[k * 128 + d];
    out[d] = s * inv;
  }
}

// ---------------- output MLP ----------------
__global__ void mlp_kernel(const float* __restrict__ cvec, const float* __restrict__ pvec,
                           const float* __restrict__ Wo, const float* __restrict__ bo,
                           const float* __restrict__ Wi, const float* __restrict__ bi,
                           float* __restrict__ out) {
  __shared__ float buf0[256], buf1[256];
  int t = threadIdx.x;
  buf0[t] = (t < 128) ? cvec[t] : pvec[t - 128];
  __syncthreads();
  {
    const float* W = Wo;                 // layer 0
    float s = bo[t];
    for (int v = 0; v < 256; ++v) s += W[t * 256 + v] * buf0[v];
    buf1[t] = fmaxf(s, 0.f);
  }
  __syncthreads();
  {
    const float* W = Wo + 256 * 256;     // layer 1
    float s = bo[256 + t];
    for (int v = 0; v < 256; ++v) s += W[t * 256 + v] * buf1[v];
    buf0[t] = fmaxf(s, 0.f);
  }
  __syncthreads();
  if (t < 2) {
    float s = bi[t];
    for (int v = 0; v < 256; ++v) s += Wi[t * 256 + v] * buf0[v];
    out[t] = s;
  }
}

extern "C" void kernel_launch(void* const* d_in, const int* in_sizes, int n_in,
                              void* d_out, int out_size, void* d_ws, size_t ws_size,
                              hipStream_t stream) {
  const int*   fingerprints = (const int*)d_in[0];
  const float* adjacency    = (const float*)d_in[1];
  const int*   words        = (const int*)d_in[2];
  const float* emb_fp       = (const float*)d_in[3];
  const float* emb_word     = (const float*)d_in[4];
  const float* Wg  = (const float*)d_in[5];
  const float* bg  = (const float*)d_in[6];
  const float* Wih = (const float*)d_in[7];
  const float* Whh = (const float*)d_in[8];
  const float* bih = (const float*)d_in[9];
  const float* bhh = (const float*)d_in[10];
  const float* Wc  = (const float*)d_in[11];
  const float* bc  = (const float*)d_in[12];
  const float* Wp  = (const float*)d_in[13];
  const float* bp  = (const float*)d_in[14];
  const float* Wo  = (const float*)d_in[15];
  const float* bo  = (const float*)d_in[16];
  const float* Wi  = (const float*)d_in[17];
  const float* bi  = (const float*)d_in[18];

  const int N = in_sizes[0];
  const int M = in_sizes[2];
  const int LGAT = in_sizes[5] / (DIM * DIM);

  float* out  = (float*)d_out;
  float* attn = out + 2;            // [N][M]: scratch during GAT, final `weights` at end

  float* ws = (float*)d_ws;
  size_t off = 0;
  auto alloc = [&](size_t nf) { float* p = ws + off; off += (nf + 3) & ~(size_t)3; return p; };
  float* xs     = alloc((size_t)N * DIM);
  float* hs     = alloc((size_t)N * DIM);
  float* wvb    = alloc((size_t)M * DIM);
  float* denom  = alloc(N);
  float* pt     = alloc((size_t)8 * N * DIM);    // K-split partials; aliased as Wx afterwards
  float* Wx     = pt;                            // [2][M][512] gate-interleaved
  float* xs_rnn = alloc((size_t)M * 2 * DIM);
  float* hp     = alloc((size_t)M * DIM);
  float* hmat   = alloc((size_t)N * DIM);
  float* bsum   = alloc(1024);
  float* wcomp  = alloc(N);
  float* wprot  = alloc(M);
  float* cvec   = alloc(DIM);
  float* pvec   = alloc(DIM);
  float* cpart  = alloc((size_t)32 * M);
  (void)ws_size; (void)n_in; (void)out_size;

  // ---- embeddings ----
  gather_rows<<<(N * 32 + 255) / 256, 256, 0, stream>>>(emb_fp, fingerprints, xs, N);
  gather_rows<<<(M * 32 + 255) / 256, 256, 0, stream>>>(emb_word, words, wvb, M);

  // ---- GAT layers ----
  for (int l = 0; l < LGAT; ++l) {
    gemm_nt<true, true, false, false><<<dim3(DIM / 64, N / 64), 256, 0, stream>>>(
        xs, Wg + (size_t)l * DIM * DIM, hs, DIM, DIM, bg + l * DIM, nullptr, 0);
    gemm_nt<false, false, true, false><<<dim3(M / 64, N / 64), 256, 0, stream>>>(
        hs, hs, attn, M, DIM, nullptr, adjacency, M);
    row_reduce<true><<<N, 256, 0, stream>>>(attn, M, M, denom, 1e-12f);
    attn_av<<<dim3(N / 32, 8), 256, 0, stream>>>(attn, M, hs, pt, M / 8, N);
    axpy_reduce<<<(N * DIM) / 256, 256, 0, stream>>>(pt, denom, xs, N * DIM);
  }

  // ---- LSTM precompute (gate-interleaved Wx) + run ----
  add_vec<<<4, 256, 0, stream>>>(bih, bhh, bsum, 1024);
  for (int d = 0; d < 2; ++d) {
    gemm_nt<false, true, false, true><<<dim3(512 / 64, M / 64), 256, 0, stream>>>(
        wvb, Wih + (size_t)d * 512 * DIM, Wx + (size_t)d * M * 512, 512, DIM,
        bsum + d * 512, nullptr, 0);
  }
  lstm_kernel<<<2, 512, 0, stream>>>(Whh, Wx, xs_rnn, M);

  // ---- cross-attention pooling ----
  gemm_nt<true, true, false, false><<<dim3(DIM / 64, M / 64), 256, 0, stream>>>(
      xs_rnn, Wp, hp, DIM, 2 * DIM, bp, nullptr, 0);
  gemm_nt<true, true, false, false><<<dim3(DIM / 64, N / 64), 256, 0, stream>>>(
      xs, Wc, hmat, DIM, DIM, bc, nullptr, 0);
  gemm_nt<false, false, false, false><<<dim3(M / 64, N / 64), 256, 0, stream>>>(
      hmat, hp, attn, M, DIM, nullptr, nullptr, 0);   // final `weights` output
  row_reduce<false><<<N, 256, 0, stream>>>(attn, M, M, wcomp, 1.f / (float)M);
  colmean_part<<<dim3(M / 256, 32), 256, 0, stream>>>(attn, M, N / 32, cpart, M);
  colmean_fin<<<M / 256, 256, 0, stream>>>(cpart, M, 32, wprot, 1.f / (float)N);
  pool_vec<<<1, 1024, 0, stream>>>(hmat, wcomp, N, cvec, 1.f / (float)N);
  pool_vec<<<1, 1024, 0, stream>>>(hp, wprot, M, pvec, 1.f / (float)M);

  // ---- output MLP ----
  mlp_kernel<<<1, 256, 0, stream>>>(cvec, pvec, Wo, bo, Wi, bi, out);
}

// Round 9
// 3785.514 us; speedup vs baseline: 1.6584x; 1.1210x over previous
//
#include <hip/hip_runtime.h>
#include <hip/hip_bf16.h>
#include <math.h>

#define DIM 128

typedef float v2f __attribute__((ext_vector_type(2)));
typedef _Float16 v2h __attribute__((ext_vector_type(2)));
typedef _Float16 v8h __attribute__((ext_vector_type(8)));

// DPP move: lane i <- lane i+N (row_shl:N, within row of 16), VALU-speed.
template<int CTRL>
__device__ inline float dpp_movf(float v) {
  int x = __builtin_amdgcn_update_dpp(0, __float_as_int(v), CTRL, 0xF, 0xF, true);
  return __int_as_float(x);
}

// 8-wide f16 dot with fp32 accumulate via v_dot2_f32_f16 (2 MAC/instr)
__device__ inline float dot8(v8h a, v8h b, float acc) {
#if __has_builtin(__builtin_amdgcn_fdot2)
  v2h a0 = {a[0], a[1]}, a1 = {a[2], a[3]}, a2 = {a[4], a[5]}, a3 = {a[6], a[7]};
  v2h b0 = {b[0], b[1]}, b1 = {b[2], b[3]}, b2 = {b[4], b[5]}, b3 = {b[6], b[7]};
  acc = __builtin_amdgcn_fdot2(a0, b0, acc, false);
  acc = __builtin_amdgcn_fdot2(a1, b1, acc, false);
  acc = __builtin_amdgcn_fdot2(a2, b2, acc, false);
  acc = __builtin_amdgcn_fdot2(a3, b3, acc, false);
#else
#pragma unroll
  for (int i = 0; i < 8; ++i) acc += (float)a[i] * (float)b[i];
#endif
  return acc;
}

// ---------------- gather rows from embedding table ----------------
__global__ void gather_rows(const float* __restrict__ table, const int* __restrict__ idx,
                            float* __restrict__ dst, int n) {
  int i = blockIdx.x * blockDim.x + threadIdx.x;   // over n*32 float4s
  int total = n * 32;
  if (i >= total) return;
  int r = i >> 5, c = i & 31;
  const float4* src = (const float4*)table + (size_t)idx[r] * 32 + c;
  ((float4*)dst)[i] = *src;
}

// ---------------- generic NT GEMM ----------------
// C[n][m] = f(dot(A[n], B[permB(m)]) + bias[permB(m)]) * adj[n][m]
// PERMB: gate-interleave permutation m=4u+g -> row 128g+u (for LSTM Wx layout)
template<bool RELU, bool HASBIAS, bool HASADJ, bool PERMB>
__global__ __launch_bounds__(256) void gemm_nt(
    const float* __restrict__ A, const float* __restrict__ B,
    float* __restrict__ C, int ldc, int K,
    const float* __restrict__ bias,
    const float* __restrict__ adj, int ldadj)
{
  __shared__ float As[64][17];
  __shared__ float Bs[64][17];
  int tid = threadIdx.x;
  int tx = tid & 15, ty = tid >> 4;
  int rowBase = blockIdx.y * 64, colBase = blockIdx.x * 64;
  int lr = tid >> 2, lk = (tid & 3) * 4;
  int brow = colBase + lr;
  if (PERMB) brow = 128 * (brow & 3) + (brow >> 2);
  float acc[4][4] = {};
  for (int k0 = 0; k0 < K; k0 += 16) {
    float4 av = *(const float4*)&A[(size_t)(rowBase + lr) * K + k0 + lk];
    float4 bv = *(const float4*)&B[(size_t)brow * K + k0 + lk];
    As[lr][lk+0]=av.x; As[lr][lk+1]=av.y; As[lr][lk+2]=av.z; As[lr][lk+3]=av.w;
    Bs[lr][lk+0]=bv.x; Bs[lr][lk+1]=bv.y; Bs[lr][lk+2]=bv.z; Bs[lr][lk+3]=bv.w;
    __syncthreads();
#pragma unroll
    for (int kk = 0; kk < 16; ++kk) {
      float a0=As[ty*4+0][kk], a1=As[ty*4+1][kk], a2=As[ty*4+2][kk], a3=As[ty*4+3][kk];
      float b0=Bs[tx*4+0][kk], b1=Bs[tx*4+1][kk], b2=Bs[tx*4+2][kk], b3=Bs[tx*4+3][kk];
      acc[0][0]+=a0*b0; acc[0][1]+=a0*b1; acc[0][2]+=a0*b2; acc[0][3]+=a0*b3;
      acc[1][0]+=a1*b0; acc[1][1]+=a1*b1; acc[1][2]+=a1*b2; acc[1][3]+=a1*b3;
      acc[2][0]+=a2*b0; acc[2][1]+=a2*b1; acc[2][2]+=a2*b2; acc[2][3]+=a2*b3;
      acc[3][0]+=a3*b0; acc[3][1]+=a3*b1; acc[3][2]+=a3*b2; acc[3][3]+=a3*b3;
    }
    __syncthreads();
  }
  int row = rowBase + ty*4, col = colBase + tx*4;
#pragma unroll
  for (int i = 0; i < 4; ++i) {
    float aj[4] = {1.f,1.f,1.f,1.f};
    if (HASADJ) {
      float4 adjv = *(const float4*)&adj[(size_t)(row+i)*ldadj + col];
      aj[0]=adjv.x; aj[1]=adjv.y; aj[2]=adjv.z; aj[3]=adjv.w;
    }
    float v[4];
#pragma unroll
    for (int j = 0; j < 4; ++j) {
      float x = acc[i][j];
      if (HASBIAS) {
        int bidx = col + j;
        if (PERMB) bidx = 128 * (bidx & 3) + (bidx >> 2);
        x += bias[bidx];
      }
      if (HASADJ) x *= aj[j];
      if (RELU) x = fmaxf(x, 0.f);
      v[j] = x;
    }
    float* cp = &C[(size_t)(row+i)*ldc + col];   // 8B-aligned even at d_out+2
    *(float2*)cp = make_float2(v[0], v[1]);
    *(float2*)(cp+2) = make_float2(v[2], v[3]);
  }
}

// ---------------- row reduction: abs-sum (with eps floor) or mean ----------------
template<bool ABS>
__global__ void row_reduce(const float* __restrict__ W, int ld, int M,
                           float* __restrict__ out, float p /*eps or 1/M*/) {
  int n = blockIdx.x;
  const float* row = W + (size_t)n * ld;
  float s = 0;
  for (int m = threadIdx.x; m < M; m += 256) {
    float v = row[m];
    s += ABS ? fabsf(v) : v;
  }
  __shared__ float red[256];
  red[threadIdx.x] = s; __syncthreads();
  for (int k = 128; k > 0; k >>= 1) {
    if (threadIdx.x < k) red[threadIdx.x] += red[threadIdx.x + k];
    __syncthreads();
  }
  if (threadIdx.x == 0) out[n] = ABS ? fmaxf(red[0], p) : red[0] * p;
}

// ---------------- column mean, 2-stage ----------------
__global__ void colmean_part(const float* __restrict__ W, int ld, int rows_per,
                             float* __restrict__ part, int M) {
  int m = blockIdx.x * blockDim.x + threadIdx.x;
  int n0 = blockIdx.y * rows_per;
  float s = 0;
  for (int n = 0; n < rows_per; ++n) s += W[(size_t)(n0 + n) * ld + m];
  part[(size_t)blockIdx.y * M + m] = s;
}
__global__ void colmean_fin(const float* __restrict__ part, int M, int nparts,
                            float* __restrict__ out, float inv) {
  int m = blockIdx.x * blockDim.x + threadIdx.x;
  float s = 0;
  for (int k = 0; k < nparts; ++k) s += part[(size_t)k * M + m];
  out[m] = s * inv;
}

// ---------------- attn @ hs with K-split ----------------
__global__ __launch_bounds__(256) void attn_av(
    const float* __restrict__ attn, int ld,
    const float* __restrict__ hs, float* __restrict__ pt,
    int chunk, int N)
{
  int r0 = blockIdx.x * 32;
  int kc = blockIdx.y;
  int m0 = kc * chunk;
  __shared__ float Hs[32][DIM];
  __shared__ float As[32][33];
  int tid = threadIdx.x;
  int tx = tid & 31, ry = tid >> 5;
  float acc[4][4] = {};
  for (int mt = 0; mt < chunk; mt += 32) {
#pragma unroll
    for (int q = 0; q < 4; ++q) {
      int f = q * 256 + tid; int hr = f >> 5, hc = (f & 31) * 4;
      *(float4*)&Hs[hr][hc] = *(const float4*)&hs[(size_t)(m0 + mt + hr) * DIM + hc];
    }
    {
      int ar = tid >> 3, ac = (tid & 7) * 4;
      const float* src = &attn[(size_t)(r0 + ar) * ld + m0 + mt + ac];
      float2 u = *(const float2*)src; float2 w = *(const float2*)(src + 2);
      As[ar][ac] = u.x; As[ar][ac+1] = u.y; As[ar][ac+2] = w.x; As[ar][ac+3] = w.y;
    }
    __syncthreads();
#pragma unroll
    for (int mm = 0; mm < 32; ++mm) {
      float4 h4 = *(const float4*)&Hs[mm][tx * 4];
      float a0 = As[ry*4+0][mm], a1 = As[ry*4+1][mm], a2 = As[ry*4+2][mm], a3 = As[ry*4+3][mm];
      acc[0][0]+=a0*h4.x; acc[0][1]+=a0*h4.y; acc[0][2]+=a0*h4.z; acc[0][3]+=a0*h4.w;
      acc[1][0]+=a1*h4.x; acc[1][1]+=a1*h4.y; acc[1][2]+=a1*h4.z; acc[1][3]+=a1*h4.w;
      acc[2][0]+=a2*h4.x; acc[2][1]+=a2*h4.y; acc[2][2]+=a2*h4.z; acc[2][3]+=a2*h4.w;
      acc[3][0]+=a3*h4.x; acc[3][1]+=a3*h4.y; acc[3][2]+=a3*h4.z; acc[3][3]+=a3*h4.w;
    }
    __syncthreads();
  }
#pragma unroll
  for (int i = 0; i < 4; ++i) {
    float4 v = make_float4(acc[i][0], acc[i][1], acc[i][2], acc[i][3]);
    *(float4*)&pt[((size_t)kc * N + r0 + ry*4 + i) * DIM + tx*4] = v;
  }
}

// xs[n][d] += (sum_kc pt[kc][n][d]) / denom[n]
__global__ void axpy_reduce(const float* __restrict__ pt, const float* __restrict__ denom,
                            float* __restrict__ xs, int total) {
  int i = blockIdx.x * blockDim.x + threadIdx.x;
  if (i >= total) return;
  float s = 0;
#pragma unroll
  for (int k = 0; k < 8; ++k) s += pt[(size_t)k * total + i];
  xs[i] += s / denom[i >> 7];
}

__global__ void add_vec(const float* __restrict__ a, const float* __restrict__ b,
                        float* __restrict__ o, int n) {
  int i = blockIdx.x * blockDim.x + threadIdx.x;
  if (i < n) o[i] = a[i] + b[i];
}

// ---------------- bidirectional LSTM v8 ----------------
// Round-5 structure, but weights converted to f16 in the prologue:
// 64 VGPRs/thread (16 named v8h) — fits INSIDE the allocator's observed
// ~88-VGPR budget at 512 threads, so residency needs no special treatment.
// Dot via v_dot2_f32_f16 (fp32 accumulate). h kept packed-f16 in LDS
// (16 broadcast b128 reads/thread/step). Wx, gates, c stay fp32.
#define REP16(X) X(0) X(1) X(2) X(3) X(4) X(5) X(6) X(7) X(8) X(9) X(10) X(11) \
  X(12) X(13) X(14) X(15)

__global__ __launch_bounds__(512, 2) void lstm_kernel(
    const float* __restrict__ Whh,   // [2][512][128] (original fp32 layout)
    const float* __restrict__ Wxp,   // [2][M][512]  gate-interleaved: col 4u+g
    float* __restrict__ xs_rnn,      // [M][256]  (stores relu(h))
    int M)
{
  int dir = blockIdx.x;
  int tid = threadIdx.x;
  int w = tid >> 6, lane = tid & 63;
  int u = w * 16 + (lane >> 2);      // hidden unit 0..127
  int g = lane & 3;                  // gate 0:i 1:f 2:g 3:o
  const float4* wrow4 = (const float4*)(Whh + ((size_t)dir * 512 + g * 128 + u) * DIM);

#define DECLW(r) v8h wh##r;
  REP16(DECLW)
#define LOADW(r) { float4 x = wrow4[2*(r)], y = wrow4[2*(r)+1]; v8h t; \
    t[0]=(_Float16)x.x; t[1]=(_Float16)x.y; t[2]=(_Float16)x.z; t[3]=(_Float16)x.w; \
    t[4]=(_Float16)y.x; t[5]=(_Float16)y.y; t[6]=(_Float16)y.z; t[7]=(_Float16)y.w; \
    wh##r = t; }
  REP16(LOADW)

  __shared__ __align__(16) _Float16 hbuf[2][DIM];
  if (tid < DIM) hbuf[0][tid] = (_Float16)0.f;
  float c = 0.f;
  __syncthreads();

  const float* WxD = Wxp + (size_t)dir * M * 512;
  int t0 = dir ? (M - 1) : 0;
  float wx = WxD[(size_t)t0 * 512 + tid];
  for (int s = 0; s < M; ++s) {
    int t = dir ? (M - 1 - s) : s;
    float wxn = 0.f;
    if (s + 1 < M) {
      int tn = dir ? (M - 2 - s) : (s + 1);
      wxn = WxD[(size_t)tn * 512 + tid];   // prefetch next step (coalesced dword)
    }
    int cur = s & 1;
    const v8h* hb8 = (const v8h*)hbuf[cur];
    float accA = 0.f, accB = 0.f;
#define DOTW(r) { v8h hv = hb8[r]; \
    if ((r) & 1) accB = dot8(wh##r, hv, accB); else accA = dot8(wh##r, hv, accA); }
    REP16(DOTW)
    float z = accA + accB + wx;
    // activation: sigmoid for i,f,o; tanh for g (tanh(z) = 2*sigmoid(2z)-1)
    float zz = (g == 2) ? 2.f * z : z;
    float sg = 1.f / (1.f + __expf(-zz));
    float av = (g == 2) ? 2.f * sg - 1.f : sg;
    // gather f,g,o gates into g==0 lane: row_shl:1/2/3 => lane i <- lane i+n
    float fv = dpp_movf<0x101>(av);
    float gv = dpp_movf<0x102>(av);
    float ov = dpp_movf<0x103>(av);
    if (g == 0) {
      c = fv * c + av * gv;
      float ec = __expf(-2.f * c);
      float th = (1.f - ec) / (1.f + ec);   // tanh(c)
      float hv = ov * th;
      hbuf[cur ^ 1][u] = (_Float16)hv;
      xs_rnn[(size_t)t * (2 * DIM) + dir * DIM + u] = fmaxf(hv, 0.f);
    }
    wx = wxn;
    __syncthreads();   // single barrier: h write visible before next-step read
  }
#undef DOTW
#undef LOADW
#undef DECLW
}

// ---------------- weighted mean pooling ----------------
__global__ void pool_vec(const float* __restrict__ mat, const float* __restrict__ wv,
                         int n, float* __restrict__ out, float inv) {
  int t = threadIdx.x; int g = t >> 7, d = t & 127;
  float acc = 0;
  for (int r = g; r < n; r += 8) acc += wv[r] * mat[(size_t)r * DIM + d];
  __shared__ float red[1024];
  red[t] = acc; __syncthreads();
  if (g == 0) {
    float s = acc;
#pragma unroll
    for (int k = 1; k < 8; ++k) s += red[k * 128 + d];
    out[d] = s * inv;
  }
}

// ---------------- output MLP ----------------
__global__ void mlp_kernel(const float* __restrict__ cvec, const float* __restrict__ pvec,
                           const float* __restrict__ Wo, const float* __restrict__ bo,
                           const float* __restrict__ Wi, const float* __restrict__ bi,
                           float* __restrict__ out) {
  __shared__ float buf0[256], buf1[256];
  int t = threadIdx.x;
  buf0[t] = (t < 128) ? cvec[t] : pvec[t - 128];
  __syncthreads();
  {
    const float* W = Wo;                 // layer 0
    float s = bo[t];
    for (int v = 0; v < 256; ++v) s += W[t * 256 + v] * buf0[v];
    buf1[t] = fmaxf(s, 0.f);
  }
  __syncthreads();
  {
    const float* W = Wo + 256 * 256;     // layer 1
    float s = bo[256 + t];
    for (int v = 0; v < 256; ++v) s += W[t * 256 + v] * buf1[v];
    buf0[t] = fmaxf(s, 0.f);
  }
  __syncthreads();
  if (t < 2) {
    float s = bi[t];
    for (int v = 0; v < 256; ++v) s += Wi[t * 256 + v] * buf0[v];
    out[t] = s;
  }
}

extern "C" void kernel_launch(void* const* d_in, const int* in_sizes, int n_in,
                              void* d_out, int out_size, void* d_ws, size_t ws_size,
                              hipStream_t stream) {
  const int*   fingerprints = (const int*)d_in[0];
  const float* adjacency    = (const float*)d_in[1];
  const int*   words        = (const int*)d_in[2];
  const float* emb_fp       = (const float*)d_in[3];
  const float* emb_word     = (const float*)d_in[4];
  const float* Wg  = (const float*)d_in[5];
  const float* bg  = (const float*)d_in[6];
  const float* Wih = (const float*)d_in[7];
  const float* Whh = (const float*)d_in[8];
  const float* bih = (const float*)d_in[9];
  const float* bhh = (const float*)d_in[10];
  const float* Wc  = (const float*)d_in[11];
  const float* bc  = (const float*)d_in[12];
  const float* Wp  = (const float*)d_in[13];
  const float* bp  = (const float*)d_in[14];
  const float* Wo  = (const float*)d_in[15];
  const float* bo  = (const float*)d_in[16];
  const float* Wi  = (const float*)d_in[17];
  const float* bi  = (const float*)d_in[18];

  const int N = in_sizes[0];
  const int M = in_sizes[2];
  const int LGAT = in_sizes[5] / (DIM * DIM);

  float* out  = (float*)d_out;
  float* attn = out + 2;            // [N][M]: scratch during GAT, final `weights` at end

  float* ws = (float*)d_ws;
  size_t off = 0;
  auto alloc = [&](size_t nf) { float* p = ws + off; off += (nf + 3) & ~(size_t)3; return p; };
  float* xs     = alloc((size_t)N * DIM);
  float* hs     = alloc((size_t)N * DIM);
  float* wvb    = alloc((size_t)M * DIM);
  float* denom  = alloc(N);
  float* pt     = alloc((size_t)8 * N * DIM);    // K-split partials; aliased as Wx afterwards
  float* Wx     = pt;                            // [2][M][512] gate-interleaved
  float* xs_rnn = alloc((size_t)M * 2 * DIM);
  float* hp     = alloc((size_t)M * DIM);
  float* hmat   = alloc((size_t)N * DIM);
  float* bsum   = alloc(1024);
  float* wcomp  = alloc(N);
  float* wprot  = alloc(M);
  float* cvec   = alloc(DIM);
  float* pvec   = alloc(DIM);
  float* cpart  = alloc((size_t)32 * M);
  (void)ws_size; (void)n_in; (void)out_size;

  // ---- embeddings ----
  gather_rows<<<(N * 32 + 255) / 256, 256, 0, stream>>>(emb_fp, fingerprints, xs, N);
  gather_rows<<<(M * 32 + 255) / 256, 256, 0, stream>>>(emb_word, words, wvb, M);

  // ---- GAT layers ----
  for (int l = 0; l < LGAT; ++l) {
    gemm_nt<true, true, false, false><<<dim3(DIM / 64, N / 64), 256, 0, stream>>>(
        xs, Wg + (size_t)l * DIM * DIM, hs, DIM, DIM, bg + l * DIM, nullptr, 0);
    gemm_nt<false, false, true, false><<<dim3(M / 64, N / 64), 256, 0, stream>>>(
        hs, hs, attn, M, DIM, nullptr, adjacency, M);
    row_reduce<true><<<N, 256, 0, stream>>>(attn, M, M, denom, 1e-12f);
    attn_av<<<dim3(N / 32, 8), 256, 0, stream>>>(attn, M, hs, pt, M / 8, N);
    axpy_reduce<<<(N * DIM) / 256, 256, 0, stream>>>(pt, denom, xs, N * DIM);
  }

  // ---- LSTM precompute (gate-interleaved Wx) + run ----
  add_vec<<<4, 256, 0, stream>>>(bih, bhh, bsum, 1024);
  for (int d = 0; d < 2; ++d) {
    gemm_nt<false, true, false, true><<<dim3(512 / 64, M / 64), 256, 0, stream>>>(
        wvb, Wih + (size_t)d * 512 * DIM, Wx + (size_t)d * M * 512, 512, DIM,
        bsum + d * 512, nullptr, 0);
  }
  lstm_kernel<<<2, 512, 0, stream>>>(Whh, Wx, xs_rnn, M);

  // ---- cross-attention pooling ----
  gemm_nt<true, true, false, false><<<dim3(DIM / 64, M / 64), 256, 0, stream>>>(
      xs_rnn, Wp, hp, DIM, 2 * DIM, bp, nullptr, 0);
  gemm_nt<true, true, false, false><<<dim3(DIM / 64, N / 64), 256, 0, stream>>>(
      xs, Wc, hmat, DIM, DIM, bc, nullptr, 0);
  gemm_nt<false, false, false, false><<<dim3(M / 64, N / 64), 256, 0, stream>>>(
      hmat, hp, attn, M, DIM, nullptr, nullptr, 0);   // final `weights` output
  row_reduce<false><<<N, 256, 0, stream>>>(attn, M, M, wcomp, 1.f / (float)M);
  colmean_part<<<dim3(M / 256, 32), 256, 0, stream>>>(attn, M, N / 32, cpart, M);
  colmean_fin<<<M / 256, 256, 0, stream>>>(cpart, M, 32, wprot, 1.f / (float)N);
  pool_vec<<<1, 1024, 0, stream>>>(hmat, wcomp, N, cvec, 1.f / (float)N);
  pool_vec<<<1, 1024, 0, stream>>>(hp, wprot, M, pvec, 1.f / (float)M);

  // ---- output MLP ----
  mlp_kernel<<<1, 256, 0, stream>>>(cvec, pvec, Wo, bo, Wi, bi, out);
}

// Round 10
// 3708.150 us; speedup vs baseline: 1.6930x; 1.0209x over previous
//
#include <hip/hip_runtime.h>
#include <hip/hip_bf16.h>
#include <math.h>

#define DIM 128

typedef float v2f __attribute__((ext_vector_type(2)));
typedef _Float16 v2h __attribute__((ext_vector_type(2)));
typedef _Float16 v8h __attribute__((ext_vector_type(8)));

// DPP move: lane i <- lane i+N (row_shl:N) or quad_perm etc. VALU-speed.
template<int CTRL>
__device__ inline float dpp_movf(float v) {
  int x = __builtin_amdgcn_update_dpp(0, __float_as_int(v), CTRL, 0xF, 0xF, true);
  return __int_as_float(x);
}
// butterfly add: v + DPP<CTRL>(v)   (0xB1 = quad_perm xor1, round-3 verified)
template<int CTRL>
__device__ inline float dpp_xadd(float v) { return v + dpp_movf<CTRL>(v); }

// 8-wide f16 dot with fp32 accumulate via v_dot2_f32_f16 (2 MAC/instr)
__device__ inline float dot8(v8h a, v8h b, float acc) {
#if __has_builtin(__builtin_amdgcn_fdot2)
  v2h a0 = {a[0], a[1]}, a1 = {a[2], a[3]}, a2 = {a[4], a[5]}, a3 = {a[6], a[7]};
  v2h b0 = {b[0], b[1]}, b1 = {b[2], b[3]}, b2 = {b[4], b[5]}, b3 = {b[6], b[7]};
  acc = __builtin_amdgcn_fdot2(a0, b0, acc, false);
  acc = __builtin_amdgcn_fdot2(a1, b1, acc, false);
  acc = __builtin_amdgcn_fdot2(a2, b2, acc, false);
  acc = __builtin_amdgcn_fdot2(a3, b3, acc, false);
#else
#pragma unroll
  for (int i = 0; i < 8; ++i) acc += (float)a[i] * (float)b[i];
#endif
  return acc;
}

// ---------------- gather rows from embedding table ----------------
__global__ void gather_rows(const float* __restrict__ table, const int* __restrict__ idx,
                            float* __restrict__ dst, int n) {
  int i = blockIdx.x * blockDim.x + threadIdx.x;   // over n*32 float4s
  int total = n * 32;
  if (i >= total) return;
  int r = i >> 5, c = i & 31;
  const float4* src = (const float4*)table + (size_t)idx[r] * 32 + c;
  ((float4*)dst)[i] = *src;
}

// ---------------- generic NT GEMM ----------------
// C[n][m] = f(dot(A[n], B[permB(m)]) + bias[permB(m)]) * adj[n][m]
// PERMB: gate-interleave permutation m=4u+g -> row 128g+u (for LSTM Wx layout)
template<bool RELU, bool HASBIAS, bool HASADJ, bool PERMB>
__global__ __launch_bounds__(256) void gemm_nt(
    const float* __restrict__ A, const float* __restrict__ B,
    float* __restrict__ C, int ldc, int K,
    const float* __restrict__ bias,
    const float* __restrict__ adj, int ldadj)
{
  __shared__ float As[64][17];
  __shared__ float Bs[64][17];
  int tid = threadIdx.x;
  int tx = tid & 15, ty = tid >> 4;
  int rowBase = blockIdx.y * 64, colBase = blockIdx.x * 64;
  int lr = tid >> 2, lk = (tid & 3) * 4;
  int brow = colBase + lr;
  if (PERMB) brow = 128 * (brow & 3) + (brow >> 2);
  float acc[4][4] = {};
  for (int k0 = 0; k0 < K; k0 += 16) {
    float4 av = *(const float4*)&A[(size_t)(rowBase + lr) * K + k0 + lk];
    float4 bv = *(const float4*)&B[(size_t)brow * K + k0 + lk];
    As[lr][lk+0]=av.x; As[lr][lk+1]=av.y; As[lr][lk+2]=av.z; As[lr][lk+3]=av.w;
    Bs[lr][lk+0]=bv.x; Bs[lr][lk+1]=bv.y; Bs[lr][lk+2]=bv.z; Bs[lr][lk+3]=bv.w;
    __syncthreads();
#pragma unroll
    for (int kk = 0; kk < 16; ++kk) {
      float a0=As[ty*4+0][kk], a1=As[ty*4+1][kk], a2=As[ty*4+2][kk], a3=As[ty*4+3][kk];
      float b0=Bs[tx*4+0][kk], b1=Bs[tx*4+1][kk], b2=Bs[tx*4+2][kk], b3=Bs[tx*4+3][kk];
      acc[0][0]+=a0*b0; acc[0][1]+=a0*b1; acc[0][2]+=a0*b2; acc[0][3]+=a0*b3;
      acc[1][0]+=a1*b0; acc[1][1]+=a1*b1; acc[1][2]+=a1*b2; acc[1][3]+=a1*b3;
      acc[2][0]+=a2*b0; acc[2][1]+=a2*b1; acc[2][2]+=a2*b2; acc[2][3]+=a2*b3;
      acc[3][0]+=a3*b0; acc[3][1]+=a3*b1; acc[3][2]+=a3*b2; acc[3][3]+=a3*b3;
    }
    __syncthreads();
  }
  int row = rowBase + ty*4, col = colBase + tx*4;
#pragma unroll
  for (int i = 0; i < 4; ++i) {
    float aj[4] = {1.f,1.f,1.f,1.f};
    if (HASADJ) {
      float4 adjv = *(const float4*)&adj[(size_t)(row+i)*ldadj + col];
      aj[0]=adjv.x; aj[1]=adjv.y; aj[2]=adjv.z; aj[3]=adjv.w;
    }
    float v[4];
#pragma unroll
    for (int j = 0; j < 4; ++j) {
      float x = acc[i][j];
      if (HASBIAS) {
        int bidx = col + j;
        if (PERMB) bidx = 128 * (bidx & 3) + (bidx >> 2);
        x += bias[bidx];
      }
      if (HASADJ) x *= aj[j];
      if (RELU) x = fmaxf(x, 0.f);
      v[j] = x;
    }
    float* cp = &C[(size_t)(row+i)*ldc + col];   // 8B-aligned even at d_out+2
    *(float2*)cp = make_float2(v[0], v[1]);
    *(float2*)(cp+2) = make_float2(v[2], v[3]);
  }
}

// ---------------- row reduction: abs-sum (with eps floor) or mean ----------------
template<bool ABS>
__global__ void row_reduce(const float* __restrict__ W, int ld, int M,
                           float* __restrict__ out, float p /*eps or 1/M*/) {
  int n = blockIdx.x;
  const float* row = W + (size_t)n * ld;
  float s = 0;
  for (int m = threadIdx.x; m < M; m += 256) {
    float v = row[m];
    s += ABS ? fabsf(v) : v;
  }
  __shared__ float red[256];
  red[threadIdx.x] = s; __syncthreads();
  for (int k = 128; k > 0; k >>= 1) {
    if (threadIdx.x < k) red[threadIdx.x] += red[threadIdx.x + k];
    __syncthreads();
  }
  if (threadIdx.x == 0) out[n] = ABS ? fmaxf(red[0], p) : red[0] * p;
}

// ---------------- column mean, 2-stage ----------------
__global__ void colmean_part(const float* __restrict__ W, int ld, int rows_per,
                             float* __restrict__ part, int M) {
  int m = blockIdx.x * blockDim.x + threadIdx.x;
  int n0 = blockIdx.y * rows_per;
  float s = 0;
  for (int n = 0; n < rows_per; ++n) s += W[(size_t)(n0 + n) * ld + m];
  part[(size_t)blockIdx.y * M + m] = s;
}
__global__ void colmean_fin(const float* __restrict__ part, int M, int nparts,
                            float* __restrict__ out, float inv) {
  int m = blockIdx.x * blockDim.x + threadIdx.x;
  float s = 0;
  for (int k = 0; k < nparts; ++k) s += part[(size_t)k * M + m];
  out[m] = s * inv;
}

// ---------------- attn @ hs with K-split ----------------
__global__ __launch_bounds__(256) void attn_av(
    const float* __restrict__ attn, int ld,
    const float* __restrict__ hs, float* __restrict__ pt,
    int chunk, int N)
{
  int r0 = blockIdx.x * 32;
  int kc = blockIdx.y;
  int m0 = kc * chunk;
  __shared__ float Hs[32][DIM];
  __shared__ float As[32][33];
  int tid = threadIdx.x;
  int tx = tid & 31, ry = tid >> 5;
  float acc[4][4] = {};
  for (int mt = 0; mt < chunk; mt += 32) {
#pragma unroll
    for (int q = 0; q < 4; ++q) {
      int f = q * 256 + tid; int hr = f >> 5, hc = (f & 31) * 4;
      *(float4*)&Hs[hr][hc] = *(const float4*)&hs[(size_t)(m0 + mt + hr) * DIM + hc];
    }
    {
      int ar = tid >> 3, ac = (tid & 7) * 4;
      const float* src = &attn[(size_t)(r0 + ar) * ld + m0 + mt + ac];
      float2 u = *(const float2*)src; float2 w = *(const float2*)(src + 2);
      As[ar][ac] = u.x; As[ar][ac+1] = u.y; As[ar][ac+2] = w.x; As[ar][ac+3] = w.y;
    }
    __syncthreads();
#pragma unroll
    for (int mm = 0; mm < 32; ++mm) {
      float4 h4 = *(const float4*)&Hs[mm][tx * 4];
      float a0 = As[ry*4+0][mm], a1 = As[ry*4+1][mm], a2 = As[ry*4+2][mm], a3 = As[ry*4+3][mm];
      acc[0][0]+=a0*h4.x; acc[0][1]+=a0*h4.y; acc[0][2]+=a0*h4.z; acc[0][3]+=a0*h4.w;
      acc[1][0]+=a1*h4.x; acc[1][1]+=a1*h4.y; acc[1][2]+=a1*h4.z; acc[1][3]+=a1*h4.w;
      acc[2][0]+=a2*h4.x; acc[2][1]+=a2*h4.y; acc[2][2]+=a2*h4.z; acc[2][3]+=a2*h4.w;
      acc[3][0]+=a3*h4.x; acc[3][1]+=a3*h4.y; acc[3][2]+=a3*h4.z; acc[3][3]+=a3*h4.w;
    }
    __syncthreads();
  }
#pragma unroll
  for (int i = 0; i < 4; ++i) {
    float4 v = make_float4(acc[i][0], acc[i][1], acc[i][2], acc[i][3]);
    *(float4*)&pt[((size_t)kc * N + r0 + ry*4 + i) * DIM + tx*4] = v;
  }
}

// xs[n][d] += (sum_kc pt[kc][n][d]) / denom[n]
__global__ void axpy_reduce(const float* __restrict__ pt, const float* __restrict__ denom,
                            float* __restrict__ xs, int total) {
  int i = blockIdx.x * blockDim.x + threadIdx.x;
  if (i >= total) return;
  float s = 0;
#pragma unroll
  for (int k = 0; k < 8; ++k) s += pt[(size_t)k * total + i];
  xs[i] += s / denom[i >> 7];
}

__global__ void add_vec(const float* __restrict__ a, const float* __restrict__ b,
                        float* __restrict__ o, int n) {
  int i = blockIdx.x * blockDim.x + threadIdx.x;
  if (i < n) o[i] = a[i] + b[i];
}

// ---------------- bidirectional LSTM v9 ----------------
// LDS-instruction-bound fix (round-9 model: 128 bcast ds_read_b128/step = 1536cyc).
// Thread = (unit u, gate-pair gp, k-half kh): lane = 4*(u%16) + 2*gp + kh.
//   gp=0 -> rows {u, 128+u} (i,f);  gp=1 -> rows {256+u, 384+u} (g,o).
//   k in [64*kh, 64*kh+64) -> 128 f16 weights = 32 VGPR (resident: << 68 budget).
// Per wave: 8 ds_read_b128 of h (2 distinct addrs/instr = 2-way, free) ->
// 64 LDS instrs/step (half of v8). kh-partials combined via quad_perm xor1
// (0xB1, round-3 verified); g,o gathered to gp0 lane via row_shl:2.
#define REP8(X) X(0) X(1) X(2) X(3) X(4) X(5) X(6) X(7)

__global__ __launch_bounds__(512, 2) void lstm_kernel(
    const float* __restrict__ Whh,   // [2][512][128] (original fp32 layout)
    const float* __restrict__ Wxp,   // [2][M][512]  gate-interleaved: col 4u+g
    float* __restrict__ xs_rnn,      // [M][256]  (stores relu(h))
    int M)
{
  int dir = blockIdx.x;
  int tid = threadIdx.x;
  int w = tid >> 6, lane = tid & 63;
  int u  = w * 16 + (lane >> 2);     // hidden unit 0..127
  int gp = (lane >> 1) & 1;          // gate pair: 0={i,f} 1={g,o}
  int kh = lane & 1;                 // k-half
  int row0 = gp ? (256 + u) : u;     // i or g
  const float* base = Whh + (size_t)dir * 512 * DIM;
  const float4* w0p = (const float4*)(base + (size_t)row0 * DIM + kh * 64);
  const float4* w1p = (const float4*)(base + (size_t)(row0 + 128) * DIM + kh * 64);

#define DECLW(r) v8h wA##r, wB##r;
  REP8(DECLW)
#define LOADW(r) { \
    float4 x = w0p[2*(r)], y = w0p[2*(r)+1]; v8h t; \
    t[0]=(_Float16)x.x; t[1]=(_Float16)x.y; t[2]=(_Float16)x.z; t[3]=(_Float16)x.w; \
    t[4]=(_Float16)y.x; t[5]=(_Float16)y.y; t[6]=(_Float16)y.z; t[7]=(_Float16)y.w; \
    wA##r = t; \
    x = w1p[2*(r)]; y = w1p[2*(r)+1]; \
    t[0]=(_Float16)x.x; t[1]=(_Float16)x.y; t[2]=(_Float16)x.z; t[3]=(_Float16)x.w; \
    t[4]=(_Float16)y.x; t[5]=(_Float16)y.y; t[6]=(_Float16)y.z; t[7]=(_Float16)y.w; \
    wB##r = t; }
  REP8(LOADW)

  __shared__ __align__(16) _Float16 hbuf[2][DIM];
  if (tid < DIM) hbuf[0][tid] = (_Float16)0.f;
  float c = 0.f;
  __syncthreads();

  const float* WxD = Wxp + (size_t)dir * M * 512;
  int wxcol = 4 * u + 2 * gp;        // even -> 8B aligned float2
  int t0 = dir ? (M - 1) : 0;
  float2 wx = *(const float2*)&WxD[(size_t)t0 * 512 + wxcol];
  for (int s = 0; s < M; ++s) {
    int t = dir ? (M - 1 - s) : s;
    float2 wxn = make_float2(0.f, 0.f);
    if (s + 1 < M) {
      int tn = dir ? (M - 2 - s) : (s + 1);
      wxn = *(const float2*)&WxD[(size_t)tn * 512 + wxcol];   // prefetch
    }
    int cur = s & 1;
    const v8h* hb8 = (const v8h*)(hbuf[cur]) + kh * 8;  // this thread's k-half
    float a0 = 0.f, a1 = 0.f;
#define DOTW(r) { v8h hv = hb8[r]; a0 = dot8(wA##r, hv, a0); a1 = dot8(wB##r, hv, a1); }
    REP8(DOTW)
    // combine k-halves (both kh lanes get the full sum), then add bias
    float z0 = dpp_xadd<0xB1>(a0) + wx.x;
    float z1 = dpp_xadd<0xB1>(a1) + wx.y;
    // gp=0: z0=i, z1=f (both sigmoid); gp=1: z0=g (tanh), z1=o (sigmoid)
    float zz0 = gp ? 2.f * z0 : z0;
    float sg0 = 1.f / (1.f + __expf(-zz0));
    float av0 = gp ? 2.f * sg0 - 1.f : sg0;
    float av1 = 1.f / (1.f + __expf(-z1));
    // gather g,o from the gp=1 pair (2 lanes to the left... right): row_shl:2
    float gv = dpp_movf<0x102>(av0);
    float ov = dpp_movf<0x102>(av1);
    if ((lane & 3) == 0) {           // gp=0, kh=0 lane does the c-update
      c = av1 * c + av0 * gv;        // c = f*c + i*g
      float ec = __expf(-2.f * c);
      float th = (1.f - ec) / (1.f + ec);   // tanh(c)
      float hv = ov * th;
      hbuf[cur ^ 1][u] = (_Float16)hv;
      xs_rnn[(size_t)t * (2 * DIM) + dir * DIM + u] = fmaxf(hv, 0.f);
    }
    wx = wxn;
    __syncthreads();   // single barrier: h write visible before next-step read
  }
#undef DOTW
#undef LOADW
#undef DECLW
}

// ---------------- weighted mean pooling ----------------
__global__ void pool_vec(const float* __restrict__ mat, const float* __restrict__ wv,
                         int n, float* __restrict__ out, float inv) {
  int t = threadIdx.x; int g = t >> 7, d = t & 127;
  float acc = 0;
  for (int r = g; r < n; r += 8) acc += wv[r] * mat[(size_t)r * DIM + d];
  __shared__ float red[1024];
  red[t] = acc; __syncthreads();
  if (g == 0) {
    float s = acc;
#pragma unroll
    for (int k = 1; k < 8; ++k) s += red[k * 128 + d];
    out[d] = s * inv;
  }
}

// ---------------- output MLP ----------------
__global__ void mlp_kernel(const float* __restrict__ cvec, const float* __restrict__ pvec,
                           const float* __restrict__ Wo, const float* __restrict__ bo,
                           const float* __restrict__ Wi, const float* __restrict__ bi,
                           float* __restrict__ out) {
  __shared__ float buf0[256], buf1[256];
  int t = threadIdx.x;
  buf0[t] = (t < 128) ? cvec[t] : pvec[t - 128];
  __syncthreads();
  {
    const float* W = Wo;                 // layer 0
    float s = bo[t];
    for (int v = 0; v < 256; ++v) s += W[t * 256 + v] * buf0[v];
    buf1[t] = fmaxf(s, 0.f);
  }
  __syncthreads();
  {
    const float* W = Wo + 256 * 256;     // layer 1
    float s = bo[256 + t];
    for (int v = 0; v < 256; ++v) s += W[t * 256 + v] * buf1[v];
    buf0[t] = fmaxf(s, 0.f);
  }
  __syncthreads();
  if (t < 2) {
    float s = bi[t];
    for (int v = 0; v < 256; ++v) s += Wi[t * 256 + v] * buf0[v];
    out[t] = s;
  }
}

extern "C" void kernel_launch(void* const* d_in, const int* in_sizes, int n_in,
                              void* d_out, int out_size, void* d_ws, size_t ws_size,
                              hipStream_t stream) {
  const int*   fingerprints = (const int*)d_in[0];
  const float* adjacency    = (const float*)d_in[1];
  const int*   words        = (const int*)d_in[2];
  const float* emb_fp       = (const float*)d_in[3];
  const float* emb_word     = (const float*)d_in[4];
  const float* Wg  = (const float*)d_in[5];
  const float* bg  = (const float*)d_in[6];
  const float* Wih = (const float*)d_in[7];
  const float* Whh = (const float*)d_in[8];
  const float* bih = (const float*)d_in[9];
  const float* bhh = (const float*)d_in[10];
  const float* Wc  = (const float*)d_in[11];
  const float* bc  = (const float*)d_in[12];
  const float* Wp  = (const float*)d_in[13];
  const float* bp  = (const float*)d_in[14];
  const float* Wo  = (const float*)d_in[15];
  const float* bo  = (const float*)d_in[16];
  const float* Wi  = (const float*)d_in[17];
  const float* bi  = (const float*)d_in[18];

  const int N = in_sizes[0];
  const int M = in_sizes[2];
  const int LGAT = in_sizes[5] / (DIM * DIM);

  float* out  = (float*)d_out;
  float* attn = out + 2;            // [N][M]: scratch during GAT, final `weights` at end

  float* ws = (float*)d_ws;
  size_t off = 0;
  auto alloc = [&](size_t nf) { float* p = ws + off; off += (nf + 3) & ~(size_t)3; return p; };
  float* xs     = alloc((size_t)N * DIM);
  float* hs     = alloc((size_t)N * DIM);
  float* wvb    = alloc((size_t)M * DIM);
  float* denom  = alloc(N);
  float* pt     = alloc((size_t)8 * N * DIM);    // K-split partials; aliased as Wx afterwards
  float* Wx     = pt;                            // [2][M][512] gate-interleaved
  float* xs_rnn = alloc((size_t)M * 2 * DIM);
  float* hp     = alloc((size_t)M * DIM);
  float* hmat   = alloc((size_t)N * DIM);
  float* bsum   = alloc(1024);
  float* wcomp  = alloc(N);
  float* wprot  = alloc(M);
  float* cvec   = alloc(DIM);
  float* pvec   = alloc(DIM);
  float* cpart  = alloc((size_t)32 * M);
  (void)ws_size; (void)n_in; (void)out_size;

  // ---- embeddings ----
  gather_rows<<<(N * 32 + 255) / 256, 256, 0, stream>>>(emb_fp, fingerprints, xs, N);
  gather_rows<<<(M * 32 + 255) / 256, 256, 0, stream>>>(emb_word, words, wvb, M);

  // ---- GAT layers ----
  for (int l = 0; l < LGAT; ++l) {
    gemm_nt<true, true, false, false><<<dim3(DIM / 64, N / 64), 256, 0, stream>>>(
        xs, Wg + (size_t)l * DIM * DIM, hs, DIM, DIM, bg + l * DIM, nullptr, 0);
    gemm_nt<false, false, true, false><<<dim3(M / 64, N / 64), 256, 0, stream>>>(
        hs, hs, attn, M, DIM, nullptr, adjacency, M);
    row_reduce<true><<<N, 256, 0, stream>>>(attn, M, M, denom, 1e-12f);
    attn_av<<<dim3(N / 32, 8), 256, 0, stream>>>(attn, M, hs, pt, M / 8, N);
    axpy_reduce<<<(N * DIM) / 256, 256, 0, stream>>>(pt, denom, xs, N * DIM);
  }

  // ---- LSTM precompute (gate-interleaved Wx) + run ----
  add_vec<<<4, 256, 0, stream>>>(bih, bhh, bsum, 1024);
  for (int d = 0; d < 2; ++d) {
    gemm_nt<false, true, false, true><<<dim3(512 / 64, M / 64), 256, 0, stream>>>(
        wvb, Wih + (size_t)d * 512 * DIM, Wx + (size_t)d * M * 512, 512, DIM,
        bsum + d * 512, nullptr, 0);
  }
  lstm_kernel<<<2, 512, 0, stream>>>(Whh, Wx, xs_rnn, M);

  // ---- cross-attention pooling ----
  gemm_nt<true, true, false, false><<<dim3(DIM / 64, M / 64), 256, 0, stream>>>(
      xs_rnn, Wp, hp, DIM, 2 * DIM, bp, nullptr, 0);
  gemm_nt<true, true, false, false><<<dim3(DIM / 64, N / 64), 256, 0, stream>>>(
      xs, Wc, hmat, DIM, DIM, bc, nullptr, 0);
  gemm_nt<false, false, false, false><<<dim3(M / 64, N / 64), 256, 0, stream>>>(
      hmat, hp, attn, M, DIM, nullptr, nullptr, 0);   // final `weights` output
  row_reduce<false><<<N, 256, 0, stream>>>(attn, M, M, wcomp, 1.f / (float)M);
  colmean_part<<<dim3(M / 256, 32), 256, 0, stream>>>(attn, M, N / 32, cpart, M);
  colmean_fin<<<M / 256, 256, 0, stream>>>(cpart, M, 32, wprot, 1.f / (float)N);
  pool_vec<<<1, 1024, 0, stream>>>(hmat, wcomp, N, cvec, 1.f / (float)N);
  pool_vec<<<1, 1024, 0, stream>>>(hp, wprot, M, pvec, 1.f / (float)M);

  // ---- output MLP ----
  mlp_kernel<<<1, 256, 0, stream>>>(cvec, pvec, Wo, bo, Wi, bi, out);
}

// Round 11
// 3411.805 us; speedup vs baseline: 1.8400x; 1.0869x over previous
//
#include <hip/hip_runtime.h>
#include <hip/hip_bf16.h>
#include <math.h>

#define DIM 128

typedef float v2f __attribute__((ext_vector_type(2)));
typedef _Float16 v2h __attribute__((ext_vector_type(2)));

// DPP move: lane i <- lane i+N (row_shl:N) or quad_perm etc. VALU-speed.
template<int CTRL>
__device__ inline float dpp_movf(float v) {
  int x = __builtin_amdgcn_update_dpp(0, __float_as_int(v), CTRL, 0xF, 0xF, true);
  return __int_as_float(x);
}
// butterfly add: v + DPP<CTRL>(v)   (0xB1 = quad_perm xor1, round-3 verified)
template<int CTRL>
__device__ inline float dpp_xadd(float v) { return v + dpp_movf<CTRL>(v); }

// 8-wide f16 dot, fp32 accum. Operands pre-packed in uint4 (2 f16/dword);
// v2h obtained by bit_cast = register alias, NO pack instructions.
__device__ inline float dot8u(uint4 a, uint4 b, float acc) {
#if __has_builtin(__builtin_amdgcn_fdot2)
  acc = __builtin_amdgcn_fdot2(__builtin_bit_cast(v2h, a.x), __builtin_bit_cast(v2h, b.x), acc, false);
  acc = __builtin_amdgcn_fdot2(__builtin_bit_cast(v2h, a.y), __builtin_bit_cast(v2h, b.y), acc, false);
  acc = __builtin_amdgcn_fdot2(__builtin_bit_cast(v2h, a.z), __builtin_bit_cast(v2h, b.z), acc, false);
  acc = __builtin_amdgcn_fdot2(__builtin_bit_cast(v2h, a.w), __builtin_bit_cast(v2h, b.w), acc, false);
#else
  const v2h* pa = (const v2h*)&a; const v2h* pb = (const v2h*)&b;
#pragma unroll
  for (int i = 0; i < 4; ++i) {
    acc += (float)pa[i][0] * (float)pb[i][0];
    acc += (float)pa[i][1] * (float)pb[i][1];
  }
#endif
  return acc;
}

// pack 2 fp32 -> 1 dword of 2 f16 (v_cvt_pkrtz_f16_f32, single instr)
__device__ inline unsigned pk2h(float a, float b) {
  return __builtin_bit_cast(unsigned, __builtin_amdgcn_cvt_pkrtz(a, b));
}

// fast sigmoid / tanh via v_rcp_f32 (replaces ~10-instr IEEE div)
__device__ inline float sigm_fast(float z) {
  return __builtin_amdgcn_rcpf(1.f + __expf(-z));
}
__device__ inline float tanh_fast(float z) {
  float e = __expf(-2.f * z);
  return (1.f - e) * __builtin_amdgcn_rcpf(1.f + e);
}

// ---------------- gather rows from embedding table ----------------
__global__ void gather_rows(const float* __restrict__ table, const int* __restrict__ idx,
                            float* __restrict__ dst, int n) {
  int i = blockIdx.x * blockDim.x + threadIdx.x;   // over n*32 float4s
  int total = n * 32;
  if (i >= total) return;
  int r = i >> 5, c = i & 31;
  const float4* src = (const float4*)table + (size_t)idx[r] * 32 + c;
  ((float4*)dst)[i] = *src;
}

// ---------------- generic NT GEMM ----------------
// C[n][m] = f(dot(A[n], B[permB(m)]) + bias[permB(m)]) * adj[n][m]
// PERMB: gate-interleave permutation m=4u+g -> row 128g+u (for LSTM Wx layout)
template<bool RELU, bool HASBIAS, bool HASADJ, bool PERMB>
__global__ __launch_bounds__(256) void gemm_nt(
    const float* __restrict__ A, const float* __restrict__ B,
    float* __restrict__ C, int ldc, int K,
    const float* __restrict__ bias,
    const float* __restrict__ adj, int ldadj)
{
  __shared__ float As[64][17];
  __shared__ float Bs[64][17];
  int tid = threadIdx.x;
  int tx = tid & 15, ty = tid >> 4;
  int rowBase = blockIdx.y * 64, colBase = blockIdx.x * 64;
  int lr = tid >> 2, lk = (tid & 3) * 4;
  int brow = colBase + lr;
  if (PERMB) brow = 128 * (brow & 3) + (brow >> 2);
  float acc[4][4] = {};
  for (int k0 = 0; k0 < K; k0 += 16) {
    float4 av = *(const float4*)&A[(size_t)(rowBase + lr) * K + k0 + lk];
    float4 bv = *(const float4*)&B[(size_t)brow * K + k0 + lk];
    As[lr][lk+0]=av.x; As[lr][lk+1]=av.y; As[lr][lk+2]=av.z; As[lr][lk+3]=av.w;
    Bs[lr][lk+0]=bv.x; Bs[lr][lk+1]=bv.y; Bs[lr][lk+2]=bv.z; Bs[lr][lk+3]=bv.w;
    __syncthreads();
#pragma unroll
    for (int kk = 0; kk < 16; ++kk) {
      float a0=As[ty*4+0][kk], a1=As[ty*4+1][kk], a2=As[ty*4+2][kk], a3=As[ty*4+3][kk];
      float b0=Bs[tx*4+0][kk], b1=Bs[tx*4+1][kk], b2=Bs[tx*4+2][kk], b3=Bs[tx*4+3][kk];
      acc[0][0]+=a0*b0; acc[0][1]+=a0*b1; acc[0][2]+=a0*b2; acc[0][3]+=a0*b3;
      acc[1][0]+=a1*b0; acc[1][1]+=a1*b1; acc[1][2]+=a1*b2; acc[1][3]+=a1*b3;
      acc[2][0]+=a2*b0; acc[2][1]+=a2*b1; acc[2][2]+=a2*b2; acc[2][3]+=a2*b3;
      acc[3][0]+=a3*b0; acc[3][1]+=a3*b1; acc[3][2]+=a3*b2; acc[3][3]+=a3*b3;
    }
    __syncthreads();
  }
  int row = rowBase + ty*4, col = colBase + tx*4;
#pragma unroll
  for (int i = 0; i < 4; ++i) {
    float aj[4] = {1.f,1.f,1.f,1.f};
    if (HASADJ) {
      float4 adjv = *(const float4*)&adj[(size_t)(row+i)*ldadj + col];
      aj[0]=adjv.x; aj[1]=adjv.y; aj[2]=adjv.z; aj[3]=adjv.w;
    }
    float v[4];
#pragma unroll
    for (int j = 0; j < 4; ++j) {
      float x = acc[i][j];
      if (HASBIAS) {
        int bidx = col + j;
        if (PERMB) bidx = 128 * (bidx & 3) + (bidx >> 2);
        x += bias[bidx];
      }
      if (HASADJ) x *= aj[j];
      if (RELU) x = fmaxf(x, 0.f);
      v[j] = x;
    }
    float* cp = &C[(size_t)(row+i)*ldc + col];   // 8B-aligned even at d_out+2
    *(float2*)cp = make_float2(v[0], v[1]);
    *(float2*)(cp+2) = make_float2(v[2], v[3]);
  }
}

// ---------------- row reduction: abs-sum (with eps floor) or mean ----------------
template<bool ABS>
__global__ void row_reduce(const float* __restrict__ W, int ld, int M,
                           float* __restrict__ out, float p /*eps or 1/M*/) {
  int n = blockIdx.x;
  const float* row = W + (size_t)n * ld;
  float s = 0;
  for (int m = threadIdx.x; m < M; m += 256) {
    float v = row[m];
    s += ABS ? fabsf(v) : v;
  }
  __shared__ float red[256];
  red[threadIdx.x] = s; __syncthreads();
  for (int k = 128; k > 0; k >>= 1) {
    if (threadIdx.x < k) red[threadIdx.x] += red[threadIdx.x + k];
    __syncthreads();
  }
  if (threadIdx.x == 0) out[n] = ABS ? fmaxf(red[0], p) : red[0] * p;
}

// ---------------- column mean, 2-stage ----------------
__global__ void colmean_part(const float* __restrict__ W, int ld, int rows_per,
                             float* __restrict__ part, int M) {
  int m = blockIdx.x * blockDim.x + threadIdx.x;
  int n0 = blockIdx.y * rows_per;
  float s = 0;
  for (int n = 0; n < rows_per; ++n) s += W[(size_t)(n0 + n) * ld + m];
  part[(size_t)blockIdx.y * M + m] = s;
}
__global__ void colmean_fin(const float* __restrict__ part, int M, int nparts,
                            float* __restrict__ out, float inv) {
  int m = blockIdx.x * blockDim.x + threadIdx.x;
  float s = 0;
  for (int k = 0; k < nparts; ++k) s += part[(size_t)k * M + m];
  out[m] = s * inv;
}

// ---------------- attn @ hs with K-split ----------------
__global__ __launch_bounds__(256) void attn_av(
    const float* __restrict__ attn, int ld,
    const float* __restrict__ hs, float* __restrict__ pt,
    int chunk, int N)
{
  int r0 = blockIdx.x * 32;
  int kc = blockIdx.y;
  int m0 = kc * chunk;
  __shared__ float Hs[32][DIM];
  __shared__ float As[32][33];
  int tid = threadIdx.x;
  int tx = tid & 31, ry = tid >> 5;
  float acc[4][4] = {};
  for (int mt = 0; mt < chunk; mt += 32) {
#pragma unroll
    for (int q = 0; q < 4; ++q) {
      int f = q * 256 + tid; int hr = f >> 5, hc = (f & 31) * 4;
      *(float4*)&Hs[hr][hc] = *(const float4*)&hs[(size_t)(m0 + mt + hr) * DIM + hc];
    }
    {
      int ar = tid >> 3, ac = (tid & 7) * 4;
      const float* src = &attn[(size_t)(r0 + ar) * ld + m0 + mt + ac];
      float2 u = *(const float2*)src; float2 w = *(const float2*)(src + 2);
      As[ar][ac] = u.x; As[ar][ac+1] = u.y; As[ar][ac+2] = w.x; As[ar][ac+3] = w.y;
    }
    __syncthreads();
#pragma unroll
    for (int mm = 0; mm < 32; ++mm) {
      float4 h4 = *(const float4*)&Hs[mm][tx * 4];
      float a0 = As[ry*4+0][mm], a1 = As[ry*4+1][mm], a2 = As[ry*4+2][mm], a3 = As[ry*4+3][mm];
      acc[0][0]+=a0*h4.x; acc[0][1]+=a0*h4.y; acc[0][2]+=a0*h4.z; acc[0][3]+=a0*h4.w;
      acc[1][0]+=a1*h4.x; acc[1][1]+=a1*h4.y; acc[1][2]+=a1*h4.z; acc[1][3]+=a1*h4.w;
      acc[2][0]+=a2*h4.x; acc[2][1]+=a2*h4.y; acc[2][2]+=a2*h4.z; acc[2][3]+=a2*h4.w;
      acc[3][0]+=a3*h4.x; acc[3][1]+=a3*h4.y; acc[3][2]+=a3*h4.z; acc[3][3]+=a3*h4.w;
    }
    __syncthreads();
  }
#pragma unroll
  for (int i = 0; i < 4; ++i) {
    float4 v = make_float4(acc[i][0], acc[i][1], acc[i][2], acc[i][3]);
    *(float4*)&pt[((size_t)kc * N + r0 + ry*4 + i) * DIM + tx*4] = v;
  }
}

// xs[n][d] += (sum_kc pt[kc][n][d]) / denom[n]
__global__ void axpy_reduce(const float* __restrict__ pt, const float* __restrict__ denom,
                            float* __restrict__ xs, int total) {
  int i = blockIdx.x * blockDim.x + threadIdx.x;
  if (i >= total) return;
  float s = 0;
#pragma unroll
  for (int k = 0; k < 8; ++k) s += pt[(size_t)k * total + i];
  xs[i] += s / denom[i >> 7];
}

__global__ void add_vec(const float* __restrict__ a, const float* __restrict__ b,
                        float* __restrict__ o, int n) {
  int i = blockIdx.x * blockDim.x + threadIdx.x;
  if (i < n) o[i] = a[i] + b[i];
}

// ---------------- bidirectional LSTM v10 ----------------
// v9 structure (u, gate-pair, k-half), but all f16 operands kept in uint4 and
// fed to v_dot2_f32_f16 via bit_cast (no per-step pack/move VALU ops), and
// activations use v_rcp_f32 instead of IEEE division. Round-10 counters showed
// ~72% VALU-busy on active CUs — this cuts per-step VALU instr ~2x.
#define REP8(X) X(0) X(1) X(2) X(3) X(4) X(5) X(6) X(7)

__global__ __launch_bounds__(512, 2) void lstm_kernel(
    const float* __restrict__ Whh,   // [2][512][128] (original fp32 layout)
    const float* __restrict__ Wxp,   // [2][M][512]  gate-interleaved: col 4u+g
    float* __restrict__ xs_rnn,      // [M][256]  (stores relu(h))
    int M)
{
  int dir = blockIdx.x;
  int tid = threadIdx.x;
  int w = tid >> 6, lane = tid & 63;
  int u  = w * 16 + (lane >> 2);     // hidden unit 0..127
  int gp = (lane >> 1) & 1;          // gate pair: 0={i,f} 1={g,o}
  int kh = lane & 1;                 // k-half
  int row0 = gp ? (256 + u) : u;     // i or g
  const float* base = Whh + (size_t)dir * 512 * DIM;
  const float4* w0p = (const float4*)(base + (size_t)row0 * DIM + kh * 64);
  const float4* w1p = (const float4*)(base + (size_t)(row0 + 128) * DIM + kh * 64);

#define DECLW(r) uint4 wA##r, wB##r;
  REP8(DECLW)
#define LOADW(r) { \
    float4 x = w0p[2*(r)], y = w0p[2*(r)+1]; \
    wA##r = make_uint4(pk2h(x.x,x.y), pk2h(x.z,x.w), pk2h(y.x,y.y), pk2h(y.z,y.w)); \
    x = w1p[2*(r)]; y = w1p[2*(r)+1]; \
    wB##r = make_uint4(pk2h(x.x,x.y), pk2h(x.z,x.w), pk2h(y.x,y.y), pk2h(y.z,y.w)); }
  REP8(LOADW)

  __shared__ __align__(16) _Float16 hbuf[2][DIM];
  if (tid < DIM) hbuf[0][tid] = (_Float16)0.f;
  float c = 0.f;
  __syncthreads();

  const float* WxD = Wxp + (size_t)dir * M * 512;
  int wxcol = 4 * u + 2 * gp;        // even -> 8B aligned float2
  int t0 = dir ? (M - 1) : 0;
  float2 wx = *(const float2*)&WxD[(size_t)t0 * 512 + wxcol];
  for (int s = 0; s < M; ++s) {
    int t = dir ? (M - 1 - s) : s;
    float2 wxn = make_float2(0.f, 0.f);
    if (s + 1 < M) {
      int tn = dir ? (M - 2 - s) : (s + 1);
      wxn = *(const float2*)&WxD[(size_t)tn * 512 + wxcol];   // prefetch
    }
    int cur = s & 1;
    const uint4* hb = (const uint4*)(hbuf[cur]) + kh * 8;  // this thread's k-half
    float a0 = 0.f, a1 = 0.f;
#define DOTW(r) { uint4 hv = hb[r]; a0 = dot8u(wA##r, hv, a0); a1 = dot8u(wB##r, hv, a1); }
    REP8(DOTW)
    // combine k-halves (both kh lanes get the full sum), then add bias
    float z0 = dpp_xadd<0xB1>(a0) + wx.x;
    float z1 = dpp_xadd<0xB1>(a1) + wx.y;
    // gp=0: z0=i, z1=f (both sigmoid); gp=1: z0=g (tanh), z1=o (sigmoid)
    float av0 = gp ? tanh_fast(z0) : sigm_fast(z0);
    float av1 = sigm_fast(z1);
    // gather g,o from the gp=1 pair: row_shl:2 => lane i <- lane i+2
    float gv = dpp_movf<0x102>(av0);
    float ov = dpp_movf<0x102>(av1);
    if ((lane & 3) == 0) {           // gp=0, kh=0 lane does the c-update
      c = av1 * c + av0 * gv;        // c = f*c + i*g
      float hv = ov * tanh_fast(c);
      hbuf[cur ^ 1][u] = (_Float16)hv;
      xs_rnn[(size_t)t * (2 * DIM) + dir * DIM + u] = fmaxf(hv, 0.f);
    }
    wx = wxn;
    __syncthreads();   // single barrier: h write visible before next-step read
  }
#undef DOTW
#undef LOADW
#undef DECLW
}

// ---------------- weighted mean pooling ----------------
__global__ void pool_vec(const float* __restrict__ mat, const float* __restrict__ wv,
                         int n, float* __restrict__ out, float inv) {
  int t = threadIdx.x; int g = t >> 7, d = t & 127;
  float acc = 0;
  for (int r = g; r < n; r += 8) acc += wv[r] * mat[(size_t)r * DIM + d];
  __shared__ float red[1024];
  red[t] = acc; __syncthreads();
  if (g == 0) {
    float s = acc;
#pragma unroll
    for (int k = 1; k < 8; ++k) s += red[k * 128 + d];
    out[d] = s * inv;
  }
}

// ---------------- output MLP ----------------
__global__ void mlp_kernel(const float* __restrict__ cvec, const float* __restrict__ pvec,
                           const float* __restrict__ Wo, const float* __restrict__ bo,
                           const float* __restrict__ Wi, const float* __restrict__ bi,
                           float* __restrict__ out) {
  __shared__ float buf0[256], buf1[256];
  int t = threadIdx.x;
  buf0[t] = (t < 128) ? cvec[t] : pvec[t - 128];
  __syncthreads();
  {
    const float* W = Wo;                 // layer 0
    float s = bo[t];
    for (int v = 0; v < 256; ++v) s += W[t * 256 + v] * buf0[v];
    buf1[t] = fmaxf(s, 0.f);
  }
  __syncthreads();
  {
    const float* W = Wo + 256 * 256;     // layer 1
    float s = bo[256 + t];
    for (int v = 0; v < 256; ++v) s += W[t * 256 + v] * buf1[v];
    buf0[t] = fmaxf(s, 0.f);
  }
  __syncthreads();
  if (t < 2) {
    float s = bi[t];
    for (int v = 0; v < 256; ++v) s += Wi[t * 256 + v] * buf0[v];
    out[t] = s;
  }
}

extern "C" void kernel_launch(void* const* d_in, const int* in_sizes, int n_in,
                              void* d_out, int out_size, void* d_ws, size_t ws_size,
                              hipStream_t stream) {
  const int*   fingerprints = (const int*)d_in[0];
  const float* adjacency    = (const float*)d_in[1];
  const int*   words        = (const int*)d_in[2];
  const float* emb_fp       = (const float*)d_in[3];
  const float* emb_word     = (const float*)d_in[4];
  const float* Wg  = (const float*)d_in[5];
  const float* bg  = (const float*)d_in[6];
  const float* Wih = (const float*)d_in[7];
  const float* Whh = (const float*)d_in[8];
  const float* bih = (const float*)d_in[9];
  const float* bhh = (const float*)d_in[10];
  const float* Wc  = (const float*)d_in[11];
  const float* bc  = (const float*)d_in[12];
  const float* Wp  = (const float*)d_in[13];
  const float* bp  = (const float*)d_in[14];
  const float* Wo  = (const float*)d_in[15];
  const float* bo  = (const float*)d_in[16];
  const float* Wi  = (const float*)d_in[17];
  const float* bi  = (const float*)d_in[18];

  const int N = in_sizes[0];
  const int M = in_sizes[2];
  const int LGAT = in_sizes[5] / (DIM * DIM);

  float* out  = (float*)d_out;
  float* attn = out + 2;            // [N][M]: scratch during GAT, final `weights` at end

  float* ws = (float*)d_ws;
  size_t off = 0;
  auto alloc = [&](size_t nf) { float* p = ws + off; off += (nf + 3) & ~(size_t)3; return p; };
  float* xs     = alloc((size_t)N * DIM);
  float* hs     = alloc((size_t)N * DIM);
  float* wvb    = alloc((size_t)M * DIM);
  float* denom  = alloc(N);
  float* pt     = alloc((size_t)8 * N * DIM);    // K-split partials; aliased as Wx afterwards
  float* Wx     = pt;                            // [2][M][512] gate-interleaved
  float* xs_rnn = alloc((size_t)M * 2 * DIM);
  float* hp     = alloc((size_t)M * DIM);
  float* hmat   = alloc((size_t)N * DIM);
  float* bsum   = alloc(1024);
  float* wcomp  = alloc(N);
  float* wprot  = alloc(M);
  float* cvec   = alloc(DIM);
  float* pvec   = alloc(DIM);
  float* cpart  = alloc((size_t)32 * M);
  (void)ws_size; (void)n_in; (void)out_size;

  // ---- embeddings ----
  gather_rows<<<(N * 32 + 255) / 256, 256, 0, stream>>>(emb_fp, fingerprints, xs, N);
  gather_rows<<<(M * 32 + 255) / 256, 256, 0, stream>>>(emb_word, words, wvb, M);

  // ---- GAT layers ----
  for (int l = 0; l < LGAT; ++l) {
    gemm_nt<true, true, false, false><<<dim3(DIM / 64, N / 64), 256, 0, stream>>>(
        xs, Wg + (size_t)l * DIM * DIM, hs, DIM, DIM, bg + l * DIM, nullptr, 0);
    gemm_nt<false, false, true, false><<<dim3(M / 64, N / 64), 256, 0, stream>>>(
        hs, hs, attn, M, DIM, nullptr, adjacency, M);
    row_reduce<true><<<N, 256, 0, stream>>>(attn, M, M, denom, 1e-12f);
    attn_av<<<dim3(N / 32, 8), 256, 0, stream>>>(attn, M, hs, pt, M / 8, N);
    axpy_reduce<<<(N * DIM) / 256, 256, 0, stream>>>(pt, denom, xs, N * DIM);
  }

  // ---- LSTM precompute (gate-interleaved Wx) + run ----
  add_vec<<<4, 256, 0, stream>>>(bih, bhh, bsum, 1024);
  for (int d = 0; d < 2; ++d) {
    gemm_nt<false, true, false, true><<<dim3(512 / 64, M / 64), 256, 0, stream>>>(
        wvb, Wih + (size_t)d * 512 * DIM, Wx + (size_t)d * M * 512, 512, DIM,
        bsum + d * 512, nullptr, 0);
  }
  lstm_kernel<<<2, 512, 0, stream>>>(Whh, Wx, xs_rnn, M);

  // ---- cross-attention pooling ----
  gemm_nt<true, true, false, false><<<dim3(DIM / 64, M / 64), 256, 0, stream>>>(
      xs_rnn, Wp, hp, DIM, 2 * DIM, bp, nullptr, 0);
  gemm_nt<true, true, false, false><<<dim3(DIM / 64, N / 64), 256, 0, stream>>>(
      xs, Wc, hmat, DIM, DIM, bc, nullptr, 0);
  gemm_nt<false, false, false, false><<<dim3(M / 64, N / 64), 256, 0, stream>>>(
      hmat, hp, attn, M, DIM, nullptr, nullptr, 0);   // final `weights` output
  row_reduce<false><<<N, 256, 0, stream>>>(attn, M, M, wcomp, 1.f / (float)M);
  colmean_part<<<dim3(M / 256, 32), 256, 0, stream>>>(attn, M, N / 32, cpart, M);
  colmean_fin<<<M / 256, 256, 0, stream>>>(cpart, M, 32, wprot, 1.f / (float)N);
  pool_vec<<<1, 1024, 0, stream>>>(hmat, wcomp, N, cvec, 1.f / (float)N);
  pool_vec<<<1, 1024, 0, stream>>>(hp, wprot, M, pvec, 1.f / (float)M);

  // ---- output MLP ----
  mlp_kernel<<<1, 256, 0, stream>>>(cvec, pvec, Wo, bo, Wi, bi, out);
}